// Round 3
// baseline (235.732 us; speedup 1.0000x reference)
//
#include <hip/hip_runtime.h>
#include <math.h>

#define D_MODEL 1024
#define NHEADS  16
#define NKV     4
#define HDIM    64
#define KVDIM   256
#define BB      2
#define NN      2048
#define MROWS   (BB*NN)        // 4096
#define QKVN    1536           // 1024 + 256 + 256
#define NTASK   (MROWS*NHEADS) // 65536
#define NSPLIT  2

typedef unsigned short ushort_t;
typedef unsigned int uint_t;
typedef float    f32x4 __attribute__((ext_vector_type(4)));
typedef _Float16 h16x8 __attribute__((ext_vector_type(8)));
typedef __fp16   fp16x2 __attribute__((ext_vector_type(2)));

#define MFMAH(A,B,C) __builtin_amdgcn_mfma_f32_16x16x32_f16((A),(B),(C),0,0,0)

// async global->LDS, 16B per lane; LDS dest = wave-uniform base + lane*16
#define GLDS(gp, lp) __builtin_amdgcn_global_load_lds( \
    (const __attribute__((address_space(1))) void*)(gp), \
    (__attribute__((address_space(3))) void*)(lp), 16, 0, 0)

__device__ __forceinline__ ushort_t f2h(float f) {
    _Float16 h = (_Float16)f;
    return *(ushort_t*)&h;
}
__device__ __forceinline__ float h2f(ushort_t u) {
    return (float)(*(const _Float16*)&u);
}
// two fp32 -> packed f16x2, single v_cvt_pkrtz_f16_f32
__device__ __forceinline__ uint_t pk2h(float a, float b) {
    fp16x2 v = __builtin_amdgcn_cvt_pkrtz(a, b);
    return *(uint_t*)&v;
}

// ---------------------------------------------------------------------------
// Fused prep: cast x->f16 (blocks [0,4096)) + 4 weight transpose-casts
// (blocks [4096,6656)). One dispatch instead of five.
// ---------------------------------------------------------------------------
__global__ __launch_bounds__(256)
void prep_kernel(const float* __restrict__ x, const float* __restrict__ Wq,
                 const float* __restrict__ Wk, const float* __restrict__ Wv,
                 const float* __restrict__ Wo, ushort_t* __restrict__ xb,
                 ushort_t* __restrict__ WqkvT, ushort_t* __restrict__ WoT)
{
    __shared__ float T[32][33];
    int blk = blockIdx.x;
    if (blk < 4096) {                      // cast: 4096*256*4 = 4M elements
        const int i = blk * 256 + threadIdx.x;
        float4 v = ((const float4*)x)[i];
        uint2 o;
        o.x = pk2h(v.x, v.y);
        o.y = pk2h(v.z, v.w);
        ((uint2*)xb)[i] = o;
        return;
    }
    blk -= 4096;
    const float* src; ushort_t* dst; int N, bx, by;
    if (blk < 1024)      { src = Wq; dst = WqkvT;                            N = D_MODEL; bx = blk & 31; by = blk >> 5; }
    else if (blk < 1280) { blk -= 1024; src = Wk; dst = WqkvT + (size_t)1024 * D_MODEL; N = KVDIM; bx = blk & 7; by = blk >> 3; }
    else if (blk < 1536) { blk -= 1280; src = Wv; dst = WqkvT + (size_t)1280 * D_MODEL; N = KVDIM; bx = blk & 7; by = blk >> 3; }
    else                 { blk -= 1536; src = Wo; dst = WoT;                 N = D_MODEL; bx = blk & 31; by = blk >> 5; }
    const int tx = threadIdx.x & 31, ty = threadIdx.x >> 5;
    const int n0 = bx * 32, k0 = by * 32;
#pragma unroll
    for (int i = 0; i < 4; i++)
        T[ty + i * 8][tx] = src[(size_t)(k0 + ty + i * 8) * N + n0 + tx];
    __syncthreads();
#pragma unroll
    for (int i = 0; i < 4; i++)
        dst[(size_t)(n0 + ty + i * 8) * D_MODEL + k0 + tx] = f2h(T[tx][ty + i * 8]);
}

// ---------------------------------------------------------------------------
// V transpose: QKVh (f16) cols [1280,1536) per batch -> Vt f16 [(b*256+d)][2048]
// ---------------------------------------------------------------------------
__global__ __launch_bounds__(256)
void vtrans_kernel(const ushort_t* __restrict__ QKVh, ushort_t* __restrict__ Vt)
{
    __shared__ ushort_t T[32][34];
    const int tx = threadIdx.x & 31, ty = threadIdx.x >> 5;
    const int n0 = blockIdx.x * 32, d0 = blockIdx.y * 32, b = blockIdx.z;
#pragma unroll
    for (int i = 0; i < 4; i++)
        T[ty + i * 8][tx] =
            QKVh[(size_t)(b * NN + n0 + ty + i * 8) * QKVN + 1280 + d0 + tx];
    __syncthreads();
#pragma unroll
    for (int i = 0; i < 4; i++)
        Vt[(size_t)(b * 256 + d0 + ty + i * 8) * NN + n0 + tx] = T[tx][ty + i * 8];
}

// ---------------------------------------------------------------------------
// RoPE (f16 in/out) + relayout for Q and K. Q gets 0.125*log2(e) folded in.
// ---------------------------------------------------------------------------
#define NQW (MROWS*NHEADS*32)   // 2,097,152
#define NKW (MROWS*NKV*32)      //   524,288
__global__ __launch_bounds__(256)
void rope_kernel(const ushort_t* __restrict__ QKVh, const float* __restrict__ Cos,
                 const float* __restrict__ Sin, ushort_t* __restrict__ Qb,
                 ushort_t* __restrict__ Kb)
{
    const float SC = 0.125f * 1.44269504f;
    int idx = blockIdx.x * 256 + threadIdx.x;
    if (idx < NQW) {
        const int row = idx >> 9, rem = idx & 511;
        const int h = rem >> 5, j = rem & 31;
        const int b = row >> 11, n = row & (NN - 1);
        const uint_t pr = *(const uint_t*)&QKVh[(size_t)row * QKVN + h * 64 + 2 * j];
        const float e = h2f((ushort_t)pr), o = h2f((ushort_t)(pr >> 16));
        const float c = Cos[n * 32 + j], s = Sin[n * 32 + j];
        ushort_t* dst = Qb + ((size_t)(b * 16 + h) * NN + n) * 64;
        dst[j]      = f2h((e * c - o * s) * SC);
        dst[j + 32] = f2h((e * s + o * c) * SC);
    } else {
        const int i2 = idx - NQW;
        const int row = i2 >> 7, rem = i2 & 127;
        const int h = rem >> 5, j = rem & 31;
        const int b = row >> 11, n = row & (NN - 1);
        const uint_t pr = *(const uint_t*)&QKVh[(size_t)row * QKVN + 1024 + h * 64 + 2 * j];
        const float e = h2f((ushort_t)pr), o = h2f((ushort_t)(pr >> 16));
        const float c = Cos[n * 32 + j], s = Sin[n * 32 + j];
        ushort_t* dst = Kb + ((size_t)(b * 4 + h) * NN + n) * 64;
        dst[j]      = f2h(e * c - o * s);
        dst[j + 32] = f2h(e * s + o * c);
    }
}

// ---------------------------------------------------------------------------
// f16 MFMA GEMM for QKV (f16 out), 128x64 tile, GLDS + XOR swizzle +
// double-buffered LDS, one barrier/iter (round-12 structure).
// ---------------------------------------------------------------------------
__global__ __launch_bounds__(256)
void gemm_qkv(const ushort_t* __restrict__ A, const ushort_t* __restrict__ Bt,
              ushort_t* __restrict__ C, int M, int N, int K)
{
    __shared__ ushort_t As[2][128 * 32];
    __shared__ ushort_t Bs[2][64 * 32];

    const int tid  = threadIdx.x;
    const int wave = tid >> 6, lane = tid & 63;
    const int quad = lane >> 4, l16 = lane & 15;
    const int rowBase = blockIdx.y * 128, colBase = blockIdx.x * 64;
    const int wm = (wave >> 1) * 64, wn = (wave & 1) * 32;

    f32x4 acc[4][2];
    const f32x4 zz = {0.f, 0.f, 0.f, 0.f};
#pragma unroll
    for (int i = 0; i < 4; i++)
#pragma unroll
        for (int j = 0; j < 2; j++) acc[i][j] = zz;

    const int sr = wave * 32 + (lane >> 2);
    const int sc = ((lane & 3) ^ ((lane >> 3) & 3)) * 8;
    const ushort_t* Ag0 = A + (size_t)(rowBase + sr) * K + sc;
    const ushort_t* Ag1 = A + (size_t)(rowBase + sr + 16) * K + sc;
    const int segA0 = (wave * 2 + 0) * 512, segA1 = (wave * 2 + 1) * 512;
    const int br = wave * 16 + (lane >> 2);
    const ushort_t* Bg0 = Bt + (size_t)(colBase + br) * K + sc;
    const int segB = wave * 512;

    const int fcol = (quad ^ ((l16 >> 1) & 3)) * 8;

    GLDS(Ag0, &As[0][segA0]);
    GLDS(Ag1, &As[0][segA1]);
    GLDS(Bg0, &Bs[0][segB]);

    for (int k0 = 0; k0 < K; k0 += 32) {
        const int cur = (k0 >> 5) & 1, nxt = cur ^ 1;
        __syncthreads();
        if (k0 + 32 < K) {
            GLDS(Ag0 + k0 + 32, &As[nxt][segA0]);
            GLDS(Ag1 + k0 + 32, &As[nxt][segA1]);
            GLDS(Bg0 + k0 + 32, &Bs[nxt][segB]);
        }

        h16x8 af[4], bf[2];
#pragma unroll
        for (int mt = 0; mt < 4; mt++)
            af[mt] = *(const h16x8*)&As[cur][(wm + mt * 16 + l16) * 32 + fcol];
#pragma unroll
        for (int nt = 0; nt < 2; nt++)
            bf[nt] = *(const h16x8*)&Bs[cur][(wn + nt * 16 + l16) * 32 + fcol];
#pragma unroll
        for (int mt = 0; mt < 4; mt++)
#pragma unroll
            for (int nt = 0; nt < 2; nt++)
                acc[mt][nt] = MFMAH(af[mt], bf[nt], acc[mt][nt]);
    }

#pragma unroll
    for (int mt = 0; mt < 4; mt++)
#pragma unroll
        for (int nt = 0; nt < 2; nt++) {
            const int row = rowBase + wm + mt * 16 + quad * 4;
            const int col = colBase + wn + nt * 16 + l16;
#pragma unroll
            for (int r = 0; r < 4; r++)
                C[(size_t)(row + r) * N + col] = f2h(acc[mt][nt][r]);
        }
}

// ---------------------------------------------------------------------------
// MFMA flash attention. Round-15: round-14 structure with the ONE fix:
// t+1 global prefetch issued AFTER __syncthreads (r14 issued it before;
// the barrier's implicit s_waitcnt vmcnt(0) drained the loads on the
// critical path every tile -> 109us). Loads now land during compute.
// Keeps: ones-MFMA lsum (VALU offload), batched per-mt P slots, 1
// barrier/tile, QBLK=256.
// ---------------------------------------------------------------------------
__global__ __launch_bounds__(256)
void attn_mfma(const ushort_t* __restrict__ Qb, const ushort_t* __restrict__ Kb,
               const ushort_t* __restrict__ Vt, ushort_t* __restrict__ Pnum,
               float* __restrict__ Pl)
{
    const int qt = blockIdx.x, h = blockIdx.y;
    const int b = blockIdx.z >> 1, chunk = blockIdx.z & 1;
    const int kvh = h >> 2;
    const int tid = threadIdx.x;
    const int wave = tid >> 6, lane = tid & 63;
    const int quad = lane >> 4, l16 = lane & 15;

    __shared__ ushort_t Ks[2][64][72];
    __shared__ ushort_t Vs[2][64][72];
    __shared__ ushort_t Ps[4][4][16 * 72];   // [wave][mt slot]

    const int row0 = qt * 256 + wave * 64;
    h16x8 qf[4][2];
#pragma unroll
    for (int mt = 0; mt < 4; mt++) {
        const ushort_t* qp =
            Qb + ((size_t)(b * 16 + h) * NN + row0 + mt * 16 + l16) * 64 + quad * 8;
        qf[mt][0] = *(const h16x8*)qp;
        qf[mt][1] = *(const h16x8*)(qp + 32);
    }

    h16x8 ones;
#pragma unroll
    for (int i = 0; i < 8; i++) ones[i] = (_Float16)1.0f;

    const ushort_t* kbase = Kb + (size_t)(b * 4 + kvh) * NN * 64;
    const ushort_t* vbase = Vt + (size_t)(b * 256 + kvh * 64) * NN;
    const int key_lo = chunk * (NN / NSPLIT);          // 1024-key chunk
    const int rot = (qt + ((h & 3) << 2)) & 15;

    const int srow = tid >> 2, sseg = (tid & 3) * 8;
    const ushort_t* kp_lane = kbase + (size_t)srow * 64 + sseg;   // + key*64
    const ushort_t* vp_lane = vbase + (size_t)srow * NN + sseg;   // + key

    const f32x4 zz = {0.f, 0.f, 0.f, 0.f};
    f32x4 o[4][4];
#pragma unroll
    for (int mt = 0; mt < 4; mt++)
#pragma unroll
        for (int dt = 0; dt < 4; dt++) o[mt][dt] = zz;
    f32x4 lsum[4];
#pragma unroll
    for (int mt = 0; mt < 4; mt++) lsum[mt] = zz;

    const int key0 = key_lo + rot * 64;
    uint4 kreg0 = *(const uint4*)(kp_lane + (size_t)key0 * 64);
    uint4 kreg1 = *(const uint4*)(kp_lane + (size_t)key0 * 64 + 32);
    uint4 vreg0 = *(const uint4*)(vp_lane + key0);
    uint4 vreg1 = *(const uint4*)(vp_lane + key0 + 32);

    for (int t = 0; t < 16; t++) {
        const int cur = t & 1;
        // stage tile t into buf[cur] (regs prefetched last iter; the vmcnt
        // wait for those loads sits here, covered by tile t-1's compute)
        *(uint4*)&Ks[cur][srow][sseg]      = kreg0;
        *(uint4*)&Ks[cur][srow][sseg + 32] = kreg1;
        *(uint4*)&Vs[cur][srow][sseg]      = vreg0;
        *(uint4*)&Vs[cur][srow][sseg + 32] = vreg1;
        __syncthreads();   // lgkm drain only (vmcnt already 0 here)

        // issue t+1 prefetch AFTER the barrier: lands during compute below
        if (t < 15) {
            const int kn = key_lo + ((rot + t + 1) & 15) * 64;
            kreg0 = *(const uint4*)(kp_lane + (size_t)kn * 64);
            kreg1 = *(const uint4*)(kp_lane + (size_t)kn * 64 + 32);
            vreg0 = *(const uint4*)(vp_lane + kn);
            vreg1 = *(const uint4*)(vp_lane + kn + 32);
        }

        // ---- Phase 1: S^T = K Q^T; exp2 + pack to registers
        uint2 pkreg[4][4];
#pragma unroll
        for (int kt = 0; kt < 4; kt++) {
            h16x8 kf0 = *(const h16x8*)&Ks[cur][kt * 16 + l16][quad * 8];
            h16x8 kf1 = *(const h16x8*)&Ks[cur][kt * 16 + l16][32 + quad * 8];
#pragma unroll
            for (int mt = 0; mt < 4; mt++) {
                f32x4 st = MFMAH(kf0, qf[mt][0], zz);
                st = MFMAH(kf1, qf[mt][1], st);
                const float p0 = exp2f(st[0]);
                const float p1 = exp2f(st[1]);
                const float p2 = exp2f(st[2]);
                const float p3 = exp2f(st[3]);
                pkreg[kt][mt].x = pk2h(p0, p1);
                pkreg[kt][mt].y = pk2h(p2, p3);
            }
        }

        // ---- Phase 2: vf reads (issue early), batch-write all P slots,
        //      then pipelined pa reads + PV/ones MFMAs
        h16x8 vf[4][2];
#pragma unroll
        for (int dt = 0; dt < 4; dt++) {
            vf[dt][0] = *(const h16x8*)&Vs[cur][dt * 16 + l16][quad * 8];
            vf[dt][1] = *(const h16x8*)&Vs[cur][dt * 16 + l16][32 + quad * 8];
        }
#pragma unroll
        for (int mt = 0; mt < 4; mt++)
#pragma unroll
            for (int kt = 0; kt < 4; kt++)
                *(uint2*)&Ps[wave][mt][l16 * 72 + kt * 16 + quad * 4] = pkreg[kt][mt];
#pragma unroll
        for (int mt = 0; mt < 4; mt++) {
            h16x8 pa0 = *(const h16x8*)&Ps[wave][mt][l16 * 72 + quad * 8];
            h16x8 pa1 = *(const h16x8*)&Ps[wave][mt][l16 * 72 + 32 + quad * 8];
#pragma unroll
            for (int dt = 0; dt < 4; dt++) {
                o[mt][dt] = MFMAH(vf[dt][0], pa0, o[mt][dt]);
                o[mt][dt] = MFMAH(vf[dt][1], pa1, o[mt][dt]);
            }
            lsum[mt] = MFMAH(ones, pa0, lsum[mt]);
            lsum[mt] = MFMAH(ones, pa1, lsum[mt]);
        }
    }

    const size_t task0 = (size_t)(b * 16 + h) * NN + row0;
    ushort_t* np = Pnum + ((size_t)chunk * NTASK + task0) * 64;
#pragma unroll
    for (int mt = 0; mt < 4; mt++) {
        const float lt = lsum[mt][0];        // col-sum of P for q=l16 (all rows equal)
        const float inv = 1.0f / lt;
#pragma unroll
        for (int dt = 0; dt < 4; dt++) {
            f32x4 v = o[mt][dt];
            uint2 pk;
            pk.x = pk2h(v[0] * inv, v[1] * inv);
            pk.y = pk2h(v[2] * inv, v[3] * inv);
            *(uint2*)&np[(size_t)(mt * 16 + l16) * 64 + dt * 16 + quad * 4] = pk;
        }
        if (quad == 0)
            Pl[(size_t)chunk * NTASK + task0 + mt * 16 + l16] = lt;
    }
}

// ---------------------------------------------------------------------------
// Wo GEMM with FUSED split-K combine: A[r][c] = (l0*ohat0 + l1*ohat1)/(l0+l1)
// computed during A-tile staging (manual ds_write into padded stride-40 LDS,
// 2 barriers/iter); B staged via GLDS + XOR swizzle, double-buffered.
// 128x64 tile, fp32 out. Deletes the combine kernel + Obuf round-trip.
// ---------------------------------------------------------------------------
__global__ __launch_bounds__(256)
void gemm_wo(const ushort_t* __restrict__ Pnum, const float* __restrict__ Pl,
             const ushort_t* __restrict__ WoT, float* __restrict__ C)
{
    __shared__ ushort_t As[2][128 * 40];   // padded rows: conflict-free b128
    __shared__ ushort_t Bs[2][64 * 32];

    const int tid  = threadIdx.x;
    const int wave = tid >> 6, lane = tid & 63;
    const int quad = lane >> 4, l16 = lane & 15;
    const int rowBase = blockIdx.y * 128, colBase = blockIdx.x * 64;
    const int wm = (wave >> 1) * 64, wn = (wave & 1) * 32;

    f32x4 acc[4][2];
    const f32x4 zz = {0.f, 0.f, 0.f, 0.f};
#pragma unroll
    for (int i = 0; i < 4; i++)
#pragma unroll
        for (int j = 0; j < 2; j++) acc[i][j] = zz;

    // A combine-staging: lane handles rows r0, r0+64; 8 cols at c8
    const int r0 = tid >> 2;             // 0..63
    const int c8 = (tid & 3) * 8;
    const int bB = rowBase >> 11;        // batch (scalar: 128 | 2048)
    const int n0 = (rowBase & (NN - 1)) + r0;

    // B staging (GLDS + swizzle)
    const int br = wave * 16 + (lane >> 2);
    const int sc = ((lane & 3) ^ ((lane >> 3) & 3)) * 8;
    const ushort_t* Bg0 = WoT + (size_t)(colBase + br) * D_MODEL + sc;
    const int segB = wave * 512;
    const int fcol = (quad ^ ((l16 >> 1) & 3)) * 8;

    uint4 a0c0, a0c1, a1c0, a1c1;
    float l00, l01, l10, l11;
    // prefetch A inputs for K-slice k0
#define PREFA(k0) { \
        const int h_ = (k0) >> 6; \
        const int d_ = ((k0) & 63) + c8; \
        const size_t t0_ = ((size_t)(bB * 16 + h_) << 11) + n0; \
        const size_t t1_ = t0_ + 64; \
        a0c0 = *(const uint4*)&Pnum[t0_ * 64 + d_]; \
        a0c1 = *(const uint4*)&Pnum[((size_t)NTASK + t0_) * 64 + d_]; \
        a1c0 = *(const uint4*)&Pnum[t1_ * 64 + d_]; \
        a1c1 = *(const uint4*)&Pnum[((size_t)NTASK + t1_) * 64 + d_]; \
        l00 = Pl[t0_]; l01 = Pl[NTASK + t0_]; \
        l10 = Pl[t1_]; l11 = Pl[NTASK + t1_]; \
    }

    PREFA(0);
    GLDS(Bg0, &Bs[0][segB]);

    for (int k0 = 0; k0 < D_MODEL; k0 += 32) {
        const int cur = (k0 >> 5) & 1, nxt = cur ^ 1;
        __syncthreads();     // prev-iter frag reads done; Bs[cur] GLDS drained

        // combine + stage A (two rows)
        {
            const float i0 = 1.f / (l00 + l01), w00 = l00 * i0, w01 = l01 * i0;
            const float i1 = 1.f / (l10 + l11), w10 = l10 * i1, w11 = l11 * i1;
            uint4 o0, o1;
            const uint_t* p0 = (const uint_t*)&a0c0;
            const uint_t* p1 = (const uint_t*)&a0c1;
            const uint_t* q0 = (const uint_t*)&a1c0;
            const uint_t* q1 = (const uint_t*)&a1c1;
            uint_t* po = (uint_t*)&o0;
            uint_t* qo = (uint_t*)&o1;
#pragma unroll
            for (int j = 0; j < 4; j++) {
                fp16x2 u = *(const fp16x2*)&p0[j];
                fp16x2 v = *(const fp16x2*)&p1[j];
                po[j] = pk2h(w00 * (float)u.x + w01 * (float)v.x,
                             w00 * (float)u.y + w01 * (float)v.y);
                fp16x2 s = *(const fp16x2*)&q0[j];
                fp16x2 r = *(const fp16x2*)&q1[j];
                qo[j] = pk2h(w10 * (float)s.x + w11 * (float)r.x,
                             w10 * (float)s.y + w11 * (float)r.y);
            }
            *(uint4*)&As[cur][r0 * 40 + c8]        = o0;
            *(uint4*)&As[cur][(r0 + 64) * 40 + c8] = o1;
        }
        __syncthreads();     // As[cur] visible to all waves

        if (k0 + 32 < D_MODEL) {
            GLDS(Bg0 + k0 + 32, &Bs[nxt][segB]);
            PREFA(k0 + 32);
        }

        h16x8 af[4], bf[2];
#pragma unroll
        for (int mt = 0; mt < 4; mt++)
            af[mt] = *(const h16x8*)&As[cur][(wm + mt * 16 + l16) * 40 + quad * 8];
#pragma unroll
        for (int nt = 0; nt < 2; nt++)
            bf[nt] = *(const h16x8*)&Bs[cur][(wn + nt * 16 + l16) * 32 + fcol];
#pragma unroll
        for (int mt = 0; mt < 4; mt++)
#pragma unroll
            for (int nt = 0; nt < 2; nt++)
                acc[mt][nt] = MFMAH(af[mt], bf[nt], acc[mt][nt]);
    }
#undef PREFA

#pragma unroll
    for (int mt = 0; mt < 4; mt++)
#pragma unroll
        for (int nt = 0; nt < 2; nt++) {
            const int row = rowBase + wm + mt * 16 + quad * 4;
            const int col = colBase + wn + nt * 16 + l16;
#pragma unroll
            for (int r = 0; r < 4; r++)
                C[(size_t)(row + r) * D_MODEL + col] = acc[mt][nt][r];
        }
}

// ---------------------------------------------------------------------------
extern "C" void kernel_launch(void* const* d_in, const int* in_sizes, int n_in,
                              void* d_out, int out_size, void* d_ws, size_t ws_size,
                              hipStream_t stream)
{
    const float* x    = (const float*)d_in[0];
    const float* cosp = (const float*)d_in[1];
    const float* sinp = (const float*)d_in[2];
    const float* Wq   = (const float*)d_in[3];
    const float* Wk   = (const float*)d_in[4];
    const float* Wv   = (const float*)d_in[5];
    const float* Wo   = (const float*)d_in[6];

    char* w = (char*)d_ws;
    ushort_t* xb     = (ushort_t*)w;                       w += (size_t)MROWS * D_MODEL * 2;
    ushort_t* WqkvT  = (ushort_t*)w;                       w += (size_t)QKVN * D_MODEL * 2;
    ushort_t* WoT    = (ushort_t*)w;                       w += (size_t)D_MODEL * D_MODEL * 2;
    ushort_t* QKVh   = (ushort_t*)w;                       w += (size_t)MROWS * QKVN * 2;
    ushort_t* Qbuf   = (ushort_t*)w;                       w += (size_t)MROWS * D_MODEL * 2;
    ushort_t* Kbuf   = (ushort_t*)w;                       w += (size_t)MROWS * KVDIM * 2;
    ushort_t* Vt     = (ushort_t*)w;                       w += (size_t)MROWS * KVDIM * 2;
    ushort_t* Pnum   = (ushort_t*)w;                       w += (size_t)NSPLIT * NTASK * 64 * 2;
    float*    Pl     = (float*)w;

    // --- fused prep (cast + 4 transposes): 1 dispatch
    prep_kernel<<<6656, 256, 0, stream>>>(x, Wq, Wk, Wv, Wo, xb, WqkvT, WoT);

    // --- fused QKV projection (f16 out)
    gemm_qkv<<<dim3(QKVN / 64, MROWS / 128), 256, 0, stream>>>(
        xb, WqkvT, QKVh, MROWS, QKVN, D_MODEL);

    // --- rope + relayout (Q,K), V transpose
    rope_kernel<<<(NQW + NKW) / 256, 256, 0, stream>>>(QKVh, cosp, sinp, Qbuf, Kbuf);
    vtrans_kernel<<<dim3(NN / 32, KVDIM / 32, BB), 256, 0, stream>>>(QKVh, Vt);

    // --- attention (split-K x2, QBLK=256, 1-barrier/tile, MFMA row-sums,
    //     prefetch AFTER barrier)
    attn_mfma<<<dim3(NN / 256, NHEADS, BB * NSPLIT), 256, 0, stream>>>(
        Qbuf, Kbuf, Vt, Pnum, Pl);

    // --- output projection with fused combine (fp32 out)
    gemm_wo<<<dim3(D_MODEL / 64, MROWS / 128), 256, 0, stream>>>(
        Pnum, Pl, WoT, (float*)d_out);
}

// Round 4
// 233.184 us; speedup vs baseline: 1.0109x; 1.0109x over previous
//
#include <hip/hip_runtime.h>
#include <math.h>

#define D_MODEL 1024
#define NHEADS  16
#define NKV     4
#define HDIM    64
#define KVDIM   256
#define BB      2
#define NN      2048
#define MROWS   (BB*NN)        // 4096
#define QKVN    1536           // 1024 + 256 + 256
#define NTASK   (MROWS*NHEADS) // 65536
#define NSPLIT  4
#define NT      ((NN/NSPLIT)/64)   // 8 key-tiles per block

typedef unsigned short ushort_t;
typedef unsigned int uint_t;
typedef float    f32x4 __attribute__((ext_vector_type(4)));
typedef _Float16 h16x8 __attribute__((ext_vector_type(8)));
typedef __fp16   fp16x2 __attribute__((ext_vector_type(2)));

#define MFMAH(A,B,C) __builtin_amdgcn_mfma_f32_16x16x32_f16((A),(B),(C),0,0,0)

// async global->LDS, 16B per lane; LDS dest = wave-uniform base + lane*16
#define GLDS(gp, lp) __builtin_amdgcn_global_load_lds( \
    (const __attribute__((address_space(1))) void*)(gp), \
    (__attribute__((address_space(3))) void*)(lp), 16, 0, 0)

__device__ __forceinline__ ushort_t f2h(float f) {
    _Float16 h = (_Float16)f;
    return *(ushort_t*)&h;
}
__device__ __forceinline__ float h2f(ushort_t u) {
    return (float)(*(const _Float16*)&u);
}
// two fp32 -> packed f16x2, single v_cvt_pkrtz_f16_f32
__device__ __forceinline__ uint_t pk2h(float a, float b) {
    fp16x2 v = __builtin_amdgcn_cvt_pkrtz(a, b);
    return *(uint_t*)&v;
}

// ---------------------------------------------------------------------------
// Fused prep: cast x->f16 (blocks [0,4096)) + 4 weight transpose-casts
// (blocks [4096,6656)). One dispatch instead of five.
// ---------------------------------------------------------------------------
__global__ __launch_bounds__(256)
void prep_kernel(const float* __restrict__ x, const float* __restrict__ Wq,
                 const float* __restrict__ Wk, const float* __restrict__ Wv,
                 const float* __restrict__ Wo, ushort_t* __restrict__ xb,
                 ushort_t* __restrict__ WqkvT, ushort_t* __restrict__ WoT)
{
    __shared__ float T[32][33];
    int blk = blockIdx.x;
    if (blk < 4096) {                      // cast: 4096*256*4 = 4M elements
        const int i = blk * 256 + threadIdx.x;
        float4 v = ((const float4*)x)[i];
        uint2 o;
        o.x = pk2h(v.x, v.y);
        o.y = pk2h(v.z, v.w);
        ((uint2*)xb)[i] = o;
        return;
    }
    blk -= 4096;
    const float* src; ushort_t* dst; int N, bx, by;
    if (blk < 1024)      { src = Wq; dst = WqkvT;                            N = D_MODEL; bx = blk & 31; by = blk >> 5; }
    else if (blk < 1280) { blk -= 1024; src = Wk; dst = WqkvT + (size_t)1024 * D_MODEL; N = KVDIM; bx = blk & 7; by = blk >> 3; }
    else if (blk < 1536) { blk -= 1280; src = Wv; dst = WqkvT + (size_t)1280 * D_MODEL; N = KVDIM; bx = blk & 7; by = blk >> 3; }
    else                 { blk -= 1536; src = Wo; dst = WoT;                 N = D_MODEL; bx = blk & 31; by = blk >> 5; }
    const int tx = threadIdx.x & 31, ty = threadIdx.x >> 5;
    const int n0 = bx * 32, k0 = by * 32;
#pragma unroll
    for (int i = 0; i < 4; i++)
        T[ty + i * 8][tx] = src[(size_t)(k0 + ty + i * 8) * N + n0 + tx];
    __syncthreads();
#pragma unroll
    for (int i = 0; i < 4; i++)
        dst[(size_t)(n0 + ty + i * 8) * D_MODEL + k0 + tx] = f2h(T[tx][ty + i * 8]);
}

// ---------------------------------------------------------------------------
// V transpose: QKVh (f16) cols [1280,1536) per batch -> Vt f16 [(b*256+d)][2048]
// ---------------------------------------------------------------------------
__global__ __launch_bounds__(256)
void vtrans_kernel(const ushort_t* __restrict__ QKVh, ushort_t* __restrict__ Vt)
{
    __shared__ ushort_t T[32][34];
    const int tx = threadIdx.x & 31, ty = threadIdx.x >> 5;
    const int n0 = blockIdx.x * 32, d0 = blockIdx.y * 32, b = blockIdx.z;
#pragma unroll
    for (int i = 0; i < 4; i++)
        T[ty + i * 8][tx] =
            QKVh[(size_t)(b * NN + n0 + ty + i * 8) * QKVN + 1280 + d0 + tx];
    __syncthreads();
#pragma unroll
    for (int i = 0; i < 4; i++)
        Vt[(size_t)(b * 256 + d0 + ty + i * 8) * NN + n0 + tx] = T[tx][ty + i * 8];
}

// ---------------------------------------------------------------------------
// RoPE (f16 in/out) + relayout for Q and K. Q gets 0.125*log2(e) folded in.
// ---------------------------------------------------------------------------
#define NQW (MROWS*NHEADS*32)   // 2,097,152
#define NKW (MROWS*NKV*32)      //   524,288
__global__ __launch_bounds__(256)
void rope_kernel(const ushort_t* __restrict__ QKVh, const float* __restrict__ Cos,
                 const float* __restrict__ Sin, ushort_t* __restrict__ Qb,
                 ushort_t* __restrict__ Kb)
{
    const float SC = 0.125f * 1.44269504f;
    int idx = blockIdx.x * 256 + threadIdx.x;
    if (idx < NQW) {
        const int row = idx >> 9, rem = idx & 511;
        const int h = rem >> 5, j = rem & 31;
        const int b = row >> 11, n = row & (NN - 1);
        const uint_t pr = *(const uint_t*)&QKVh[(size_t)row * QKVN + h * 64 + 2 * j];
        const float e = h2f((ushort_t)pr), o = h2f((ushort_t)(pr >> 16));
        const float c = Cos[n * 32 + j], s = Sin[n * 32 + j];
        ushort_t* dst = Qb + ((size_t)(b * 16 + h) * NN + n) * 64;
        dst[j]      = f2h((e * c - o * s) * SC);
        dst[j + 32] = f2h((e * s + o * c) * SC);
    } else {
        const int i2 = idx - NQW;
        const int row = i2 >> 7, rem = i2 & 127;
        const int h = rem >> 5, j = rem & 31;
        const int b = row >> 11, n = row & (NN - 1);
        const uint_t pr = *(const uint_t*)&QKVh[(size_t)row * QKVN + 1024 + h * 64 + 2 * j];
        const float e = h2f((ushort_t)pr), o = h2f((ushort_t)(pr >> 16));
        const float c = Cos[n * 32 + j], s = Sin[n * 32 + j];
        ushort_t* dst = Kb + ((size_t)(b * 4 + h) * NN + n) * 64;
        dst[j]      = f2h(e * c - o * s);
        dst[j + 32] = f2h(e * s + o * c);
    }
}

// ---------------------------------------------------------------------------
// f16 MFMA GEMM for QKV (f16 out), 128x64 tile, GLDS + XOR swizzle +
// double-buffered LDS, one barrier/iter (round-12 structure).
// ---------------------------------------------------------------------------
__global__ __launch_bounds__(256)
void gemm_qkv(const ushort_t* __restrict__ A, const ushort_t* __restrict__ Bt,
              ushort_t* __restrict__ C, int M, int N, int K)
{
    __shared__ ushort_t As[2][128 * 32];
    __shared__ ushort_t Bs[2][64 * 32];

    const int tid  = threadIdx.x;
    const int wave = tid >> 6, lane = tid & 63;
    const int quad = lane >> 4, l16 = lane & 15;
    const int rowBase = blockIdx.y * 128, colBase = blockIdx.x * 64;
    const int wm = (wave >> 1) * 64, wn = (wave & 1) * 32;

    f32x4 acc[4][2];
    const f32x4 zz = {0.f, 0.f, 0.f, 0.f};
#pragma unroll
    for (int i = 0; i < 4; i++)
#pragma unroll
        for (int j = 0; j < 2; j++) acc[i][j] = zz;

    const int sr = wave * 32 + (lane >> 2);
    const int sc = ((lane & 3) ^ ((lane >> 3) & 3)) * 8;
    const ushort_t* Ag0 = A + (size_t)(rowBase + sr) * K + sc;
    const ushort_t* Ag1 = A + (size_t)(rowBase + sr + 16) * K + sc;
    const int segA0 = (wave * 2 + 0) * 512, segA1 = (wave * 2 + 1) * 512;
    const int br = wave * 16 + (lane >> 2);
    const ushort_t* Bg0 = Bt + (size_t)(colBase + br) * K + sc;
    const int segB = wave * 512;

    const int fcol = (quad ^ ((l16 >> 1) & 3)) * 8;

    GLDS(Ag0, &As[0][segA0]);
    GLDS(Ag1, &As[0][segA1]);
    GLDS(Bg0, &Bs[0][segB]);

    for (int k0 = 0; k0 < K; k0 += 32) {
        const int cur = (k0 >> 5) & 1, nxt = cur ^ 1;
        __syncthreads();
        if (k0 + 32 < K) {
            GLDS(Ag0 + k0 + 32, &As[nxt][segA0]);
            GLDS(Ag1 + k0 + 32, &As[nxt][segA1]);
            GLDS(Bg0 + k0 + 32, &Bs[nxt][segB]);
        }

        h16x8 af[4], bf[2];
#pragma unroll
        for (int mt = 0; mt < 4; mt++)
            af[mt] = *(const h16x8*)&As[cur][(wm + mt * 16 + l16) * 32 + fcol];
#pragma unroll
        for (int nt = 0; nt < 2; nt++)
            bf[nt] = *(const h16x8*)&Bs[cur][(wn + nt * 16 + l16) * 32 + fcol];
#pragma unroll
        for (int mt = 0; mt < 4; mt++)
#pragma unroll
            for (int nt = 0; nt < 2; nt++)
                acc[mt][nt] = MFMAH(af[mt], bf[nt], acc[mt][nt]);
    }

#pragma unroll
    for (int mt = 0; mt < 4; mt++)
#pragma unroll
        for (int nt = 0; nt < 2; nt++) {
            const int row = rowBase + wm + mt * 16 + quad * 4;
            const int col = colBase + wn + nt * 16 + l16;
#pragma unroll
            for (int r = 0; r < 4; r++)
                C[(size_t)(row + r) * N + col] = f2h(acc[mt][nt][r]);
        }
}

// ---------------------------------------------------------------------------
// MFMA flash attention — EXACT round-0 core (71.6us structure: 2 barriers/
// tile, single-buffered K/V, slot-reuse P, VALU lacc, shfl reduce), with
// ONLY NSPLIT 2->4: grid 512 -> 1024 blocks. VGPR=120 (<=128 -> 4 waves/
// SIMD) and LDS=27.6KB allow 4 blocks/CU resident; the 512-block grid was
// the residency limiter, not the kernel. Per-wave tile work unchanged
// (r13 showed halving per-wave work regresses; this doesn't).
// ---------------------------------------------------------------------------
__global__ __launch_bounds__(256)
void attn_mfma(const ushort_t* __restrict__ Qb, const ushort_t* __restrict__ Kb,
               const ushort_t* __restrict__ Vt, ushort_t* __restrict__ Pnum,
               float* __restrict__ Pl)
{
    const int qt = blockIdx.x, h = blockIdx.y;
    const int b = blockIdx.z >> 2, chunk = blockIdx.z & 3;
    const int kvh = h >> 2;
    const int tid = threadIdx.x;
    const int wave = tid >> 6, lane = tid & 63;
    const int quad = lane >> 4, l16 = lane & 15;

    __shared__ ushort_t Ks[64][72];
    __shared__ ushort_t Vs[64][72];
    __shared__ ushort_t Ps[4][16 * 72];
    ushort_t* ps = &Ps[wave][0];

    const int row0 = qt * 256 + wave * 64;
    h16x8 qf[4][2];
#pragma unroll
    for (int mt = 0; mt < 4; mt++) {
        const ushort_t* qp =
            Qb + ((size_t)(b * 16 + h) * NN + row0 + mt * 16 + l16) * 64 + quad * 8;
        qf[mt][0] = *(const h16x8*)qp;
        qf[mt][1] = *(const h16x8*)(qp + 32);
    }

    const ushort_t* kbase = Kb + (size_t)(b * 4 + kvh) * NN * 64;
    const ushort_t* vbase = Vt + (size_t)(b * 256 + kvh * 64) * NN;
    const int key_lo = chunk * (NN / NSPLIT);          // 512-key chunk
    const int rot = (qt + ((h & 3) << 2)) & (NT - 1);

    const int srow = tid >> 2, sseg = (tid & 3) * 8;

    const f32x4 zz = {0.f, 0.f, 0.f, 0.f};
    f32x4 o[4][4];
#pragma unroll
    for (int mt = 0; mt < 4; mt++)
#pragma unroll
        for (int dt = 0; dt < 4; dt++) o[mt][dt] = zz;
    float lacc[4] = {0.f, 0.f, 0.f, 0.f};

    int key0 = key_lo + rot * 64;
    const ushort_t* kp0 = kbase + (size_t)(key0 + srow) * 64 + sseg;
    const ushort_t* vp0 = vbase + (size_t)srow * NN + key0 + sseg;
    uint4 kreg0 = *(const uint4*)kp0;
    uint4 kreg1 = *(const uint4*)(kp0 + 32);
    uint4 vreg0 = *(const uint4*)vp0;
    uint4 vreg1 = *(const uint4*)(vp0 + 32);

    for (int t = 0; t < NT; t++) {
        __syncthreads();
        *(uint4*)&Ks[srow][sseg]      = kreg0;
        *(uint4*)&Ks[srow][sseg + 32] = kreg1;
        *(uint4*)&Vs[srow][sseg]      = vreg0;
        *(uint4*)&Vs[srow][sseg + 32] = vreg1;
        __syncthreads();

        if (t < NT - 1) {
            const int kn = key_lo + ((rot + t + 1) & (NT - 1)) * 64;
            const ushort_t* kpn = kbase + (size_t)(kn + srow) * 64 + sseg;
            const ushort_t* vpn = vbase + (size_t)srow * NN + kn + sseg;
            kreg0 = *(const uint4*)kpn;
            kreg1 = *(const uint4*)(kpn + 32);
            vreg0 = *(const uint4*)vpn;
            vreg1 = *(const uint4*)(vpn + 32);
        }

        // ---- Phase 1: S^T = K Q^T; exp2 + pack to registers
        uint2 pkreg[4][4];
#pragma unroll
        for (int kt = 0; kt < 4; kt++) {
            h16x8 kf0 = *(const h16x8*)&Ks[kt * 16 + l16][quad * 8];
            h16x8 kf1 = *(const h16x8*)&Ks[kt * 16 + l16][32 + quad * 8];
#pragma unroll
            for (int mt = 0; mt < 4; mt++) {
                f32x4 st = MFMAH(kf0, qf[mt][0], zz);
                st = MFMAH(kf1, qf[mt][1], st);
                const float p0 = exp2f(st[0]);
                const float p1 = exp2f(st[1]);
                const float p2 = exp2f(st[2]);
                const float p3 = exp2f(st[3]);
                lacc[mt] += (p0 + p1) + (p2 + p3);
                pkreg[kt][mt].x = pk2h(p0, p1);
                pkreg[kt][mt].y = pk2h(p2, p3);
            }
        }

        // ---- Phase 2: per mt: write P^T slot, read A-frags, PV MFMAs
        h16x8 vf[4][2];
#pragma unroll
        for (int dt = 0; dt < 4; dt++) {
            vf[dt][0] = *(const h16x8*)&Vs[dt * 16 + l16][quad * 8];
            vf[dt][1] = *(const h16x8*)&Vs[dt * 16 + l16][32 + quad * 8];
        }
#pragma unroll
        for (int mt = 0; mt < 4; mt++) {
#pragma unroll
            for (int kt = 0; kt < 4; kt++)
                *(uint2*)&ps[l16 * 72 + kt * 16 + quad * 4] = pkreg[kt][mt];
            h16x8 pa0 = *(const h16x8*)&ps[l16 * 72 + quad * 8];
            h16x8 pa1 = *(const h16x8*)&ps[l16 * 72 + 32 + quad * 8];
#pragma unroll
            for (int dt = 0; dt < 4; dt++) {
                o[mt][dt] = MFMAH(vf[dt][0], pa0, o[mt][dt]);
                o[mt][dt] = MFMAH(vf[dt][1], pa1, o[mt][dt]);
            }
        }
    }

#pragma unroll
    for (int mt = 0; mt < 4; mt++) {
        lacc[mt] += __shfl_xor(lacc[mt], 16, 64);
        lacc[mt] += __shfl_xor(lacc[mt], 32, 64);
    }

    const size_t task0 = (size_t)(b * 16 + h) * NN + row0;
    ushort_t* np = Pnum + ((size_t)chunk * NTASK + task0) * 64;
#pragma unroll
    for (int mt = 0; mt < 4; mt++) {
        const float inv = 1.0f / lacc[mt];
#pragma unroll
        for (int dt = 0; dt < 4; dt++) {
            f32x4 v = o[mt][dt];
            uint2 pk;
            pk.x = pk2h(v[0] * inv, v[1] * inv);
            pk.y = pk2h(v[2] * inv, v[3] * inv);
            *(uint2*)&np[(size_t)(mt * 16 + l16) * 64 + dt * 16 + quad * 4] = pk;
        }
        if (quad == 0)
            Pl[(size_t)chunk * NTASK + task0 + mt * 16 + l16] = lacc[mt];
    }
}

// ---------------------------------------------------------------------------
// Wo GEMM with FUSED 4-way split-K combine: A[r][c] = sum_c l_c*ohat_c / sum_c l_c
// computed during A-tile staging (manual ds_write into padded stride-40 LDS,
// 2 barriers/iter); B staged via GLDS + XOR swizzle, double-buffered.
// 128x64 tile, fp32 out.
// ---------------------------------------------------------------------------
__global__ __launch_bounds__(256)
void gemm_wo(const ushort_t* __restrict__ Pnum, const float* __restrict__ Pl,
             const ushort_t* __restrict__ WoT, float* __restrict__ C)
{
    __shared__ ushort_t As[2][128 * 40];   // padded rows: conflict-free b128
    __shared__ ushort_t Bs[2][64 * 32];

    const int tid  = threadIdx.x;
    const int wave = tid >> 6, lane = tid & 63;
    const int quad = lane >> 4, l16 = lane & 15;
    const int rowBase = blockIdx.y * 128, colBase = blockIdx.x * 64;
    const int wm = (wave >> 1) * 64, wn = (wave & 1) * 32;

    f32x4 acc[4][2];
    const f32x4 zz = {0.f, 0.f, 0.f, 0.f};
#pragma unroll
    for (int i = 0; i < 4; i++)
#pragma unroll
        for (int j = 0; j < 2; j++) acc[i][j] = zz;

    // A combine-staging: lane handles rows r0, r0+64; 8 cols at c8
    const int r0 = tid >> 2;             // 0..63
    const int c8 = (tid & 3) * 8;
    const int bB = rowBase >> 11;        // batch (scalar: 128 | 2048)
    const int n0 = (rowBase & (NN - 1)) + r0;

    // B staging (GLDS + swizzle)
    const int br = wave * 16 + (lane >> 2);
    const int sc = ((lane & 3) ^ ((lane >> 3) & 3)) * 8;
    const ushort_t* Bg0 = WoT + (size_t)(colBase + br) * D_MODEL + sc;
    const int segB = wave * 512;
    const int fcol = (quad ^ ((l16 >> 1) & 3)) * 8;

    uint4 a0c[4], a1c[4];
    float l0[4], l1[4];
    // prefetch A inputs for K-slice k0 (4 split-K chunks, 2 rows)
#define PREFA(k0) { \
        const int h_ = (k0) >> 6; \
        const int d_ = ((k0) & 63) + c8; \
        const size_t t0_ = ((size_t)(bB * 16 + h_) << 11) + n0; \
        const size_t t1_ = t0_ + 64; \
        a0c[0] = *(const uint4*)&Pnum[t0_ * 64 + d_]; \
        a0c[1] = *(const uint4*)&Pnum[((size_t)NTASK + t0_) * 64 + d_]; \
        a0c[2] = *(const uint4*)&Pnum[((size_t)2 * NTASK + t0_) * 64 + d_]; \
        a0c[3] = *(const uint4*)&Pnum[((size_t)3 * NTASK + t0_) * 64 + d_]; \
        a1c[0] = *(const uint4*)&Pnum[t1_ * 64 + d_]; \
        a1c[1] = *(const uint4*)&Pnum[((size_t)NTASK + t1_) * 64 + d_]; \
        a1c[2] = *(const uint4*)&Pnum[((size_t)2 * NTASK + t1_) * 64 + d_]; \
        a1c[3] = *(const uint4*)&Pnum[((size_t)3 * NTASK + t1_) * 64 + d_]; \
        l0[0] = Pl[t0_];  l0[1] = Pl[(size_t)NTASK + t0_]; \
        l0[2] = Pl[(size_t)2 * NTASK + t0_];  l0[3] = Pl[(size_t)3 * NTASK + t0_]; \
        l1[0] = Pl[t1_];  l1[1] = Pl[(size_t)NTASK + t1_]; \
        l1[2] = Pl[(size_t)2 * NTASK + t1_];  l1[3] = Pl[(size_t)3 * NTASK + t1_]; \
    }

    PREFA(0);
    GLDS(Bg0, &Bs[0][segB]);

    for (int k0 = 0; k0 < D_MODEL; k0 += 32) {
        const int cur = (k0 >> 5) & 1, nxt = cur ^ 1;
        __syncthreads();     // prev-iter frag reads done; Bs[cur] GLDS drained

        // combine + stage A (two rows, 4 chunks, f32 accumulation)
        {
            const float s0 = (l0[0] + l0[1]) + (l0[2] + l0[3]);
            const float s1 = (l1[0] + l1[1]) + (l1[2] + l1[3]);
            const float i0 = 1.f / s0, i1 = 1.f / s1;
            float w0[4], w1[4];
#pragma unroll
            for (int c = 0; c < 4; c++) { w0[c] = l0[c] * i0; w1[c] = l1[c] * i1; }
            uint4 o0, o1;
            uint_t* po = (uint_t*)&o0;
            uint_t* qo = (uint_t*)&o1;
#pragma unroll
            for (int j = 0; j < 4; j++) {
                float x0 = 0.f, y0 = 0.f, x1 = 0.f, y1 = 0.f;
#pragma unroll
                for (int c = 0; c < 4; c++) {
                    fp16x2 u = *(const fp16x2*)&((const uint_t*)&a0c[c])[j];
                    x0 += w0[c] * (float)u.x;  y0 += w0[c] * (float)u.y;
                    fp16x2 v = *(const fp16x2*)&((const uint_t*)&a1c[c])[j];
                    x1 += w1[c] * (float)v.x;  y1 += w1[c] * (float)v.y;
                }
                po[j] = pk2h(x0, y0);
                qo[j] = pk2h(x1, y1);
            }
            *(uint4*)&As[cur][r0 * 40 + c8]        = o0;
            *(uint4*)&As[cur][(r0 + 64) * 40 + c8] = o1;
        }
        __syncthreads();     // As[cur] visible to all waves

        if (k0 + 32 < D_MODEL) {
            GLDS(Bg0 + k0 + 32, &Bs[nxt][segB]);
            PREFA(k0 + 32);
        }

        h16x8 af[4], bf[2];
#pragma unroll
        for (int mt = 0; mt < 4; mt++)
            af[mt] = *(const h16x8*)&As[cur][(wm + mt * 16 + l16) * 40 + quad * 8];
#pragma unroll
        for (int nt = 0; nt < 2; nt++)
            bf[nt] = *(const h16x8*)&Bs[cur][(wn + nt * 16 + l16) * 32 + fcol];
#pragma unroll
        for (int mt = 0; mt < 4; mt++)
#pragma unroll
            for (int nt = 0; nt < 2; nt++)
                acc[mt][nt] = MFMAH(af[mt], bf[nt], acc[mt][nt]);
    }
#undef PREFA

#pragma unroll
    for (int mt = 0; mt < 4; mt++)
#pragma unroll
        for (int nt = 0; nt < 2; nt++) {
            const int row = rowBase + wm + mt * 16 + quad * 4;
            const int col = colBase + wn + nt * 16 + l16;
#pragma unroll
            for (int r = 0; r < 4; r++)
                C[(size_t)(row + r) * D_MODEL + col] = acc[mt][nt][r];
        }
}

// ---------------------------------------------------------------------------
extern "C" void kernel_launch(void* const* d_in, const int* in_sizes, int n_in,
                              void* d_out, int out_size, void* d_ws, size_t ws_size,
                              hipStream_t stream)
{
    const float* x    = (const float*)d_in[0];
    const float* cosp = (const float*)d_in[1];
    const float* sinp = (const float*)d_in[2];
    const float* Wq   = (const float*)d_in[3];
    const float* Wk   = (const float*)d_in[4];
    const float* Wv   = (const float*)d_in[5];
    const float* Wo   = (const float*)d_in[6];

    char* w = (char*)d_ws;
    ushort_t* xb     = (ushort_t*)w;                       w += (size_t)MROWS * D_MODEL * 2;
    ushort_t* WqkvT  = (ushort_t*)w;                       w += (size_t)QKVN * D_MODEL * 2;
    ushort_t* WoT    = (ushort_t*)w;                       w += (size_t)D_MODEL * D_MODEL * 2;
    ushort_t* QKVh   = (ushort_t*)w;                       w += (size_t)MROWS * QKVN * 2;
    ushort_t* Qbuf   = (ushort_t*)w;                       w += (size_t)MROWS * D_MODEL * 2;
    ushort_t* Kbuf   = (ushort_t*)w;                       w += (size_t)MROWS * KVDIM * 2;
    ushort_t* Vt     = (ushort_t*)w;                       w += (size_t)MROWS * KVDIM * 2;
    ushort_t* Pnum   = (ushort_t*)w;                       w += (size_t)NSPLIT * NTASK * 64 * 2;
    float*    Pl     = (float*)w;

    // --- fused prep (cast + 4 transposes): 1 dispatch
    prep_kernel<<<6656, 256, 0, stream>>>(x, Wq, Wk, Wv, Wo, xb, WqkvT, WoT);

    // --- fused QKV projection (f16 out)
    gemm_qkv<<<dim3(QKVN / 64, MROWS / 128), 256, 0, stream>>>(
        xb, WqkvT, QKVh, MROWS, QKVN, D_MODEL);

    // --- rope + relayout (Q,K), V transpose
    rope_kernel<<<(NQW + NKW) / 256, 256, 0, stream>>>(QKVh, cosp, sinp, Qbuf, Kbuf);
    vtrans_kernel<<<dim3(NN / 32, KVDIM / 32, BB), 256, 0, stream>>>(QKVh, Vt);

    // --- attention (split-K x4: 1024 blocks -> 4 blocks/CU resident,
    //     r0 inner loop verbatim)
    attn_mfma<<<dim3(NN / 256, NHEADS, BB * NSPLIT), 256, 0, stream>>>(
        Qbuf, Kbuf, Vt, Pnum, Pl);

    // --- output projection with fused 4-way combine (fp32 out)
    gemm_wo<<<dim3(D_MODEL / 64, MROWS / 128), 256, 0, stream>>>(
        Pnum, Pl, WoT, (float*)d_out);
}

// Round 6
// 211.317 us; speedup vs baseline: 1.1155x; 1.1035x over previous
//
#include <hip/hip_runtime.h>
#include <math.h>

#define D_MODEL 1024
#define NHEADS  16
#define NKV     4
#define HDIM    64
#define KVDIM   256
#define BB      2
#define NN      2048
#define MROWS   (BB*NN)        // 4096
#define QKVN    1536           // 1024 + 256 + 256
#define NTASK   (MROWS*NHEADS) // 65536
#define NSPLIT  2

typedef unsigned short ushort_t;
typedef unsigned int uint_t;
typedef float    f32x4 __attribute__((ext_vector_type(4)));
typedef _Float16 h16x8 __attribute__((ext_vector_type(8)));
typedef _Float16 h16x4 __attribute__((ext_vector_type(4)));
typedef __fp16   fp16x2 __attribute__((ext_vector_type(2)));

#define MFMAH(A,B,C)  __builtin_amdgcn_mfma_f32_16x16x32_f16((A),(B),(C),0,0,0)
// NOTE spelling: carried-forward GCN-era intrinsic has NO underscore before f16
#define MFMA16(A,B,C) __builtin_amdgcn_mfma_f32_16x16x16f16((A),(B),(C),0,0,0)

// async global->LDS, 16B per lane; LDS dest = wave-uniform base + lane*16
#define GLDS(gp, lp) __builtin_amdgcn_global_load_lds( \
    (const __attribute__((address_space(1))) void*)(gp), \
    (__attribute__((address_space(3))) void*)(lp), 16, 0, 0)

__device__ __forceinline__ ushort_t f2h(float f) {
    _Float16 h = (_Float16)f;
    return *(ushort_t*)&h;
}
__device__ __forceinline__ float h2f(ushort_t u) {
    return (float)(*(const _Float16*)&u);
}
// two fp32 -> packed f16x2, single v_cvt_pkrtz_f16_f32
__device__ __forceinline__ uint_t pk2h(float a, float b) {
    fp16x2 v = __builtin_amdgcn_cvt_pkrtz(a, b);
    return *(uint_t*)&v;
}

// ---------------------------------------------------------------------------
// Fused prep: cast x->f16 (blocks [0,4096)) + 4 weight transpose-casts
// (blocks [4096,6656)). One dispatch instead of five.
// ---------------------------------------------------------------------------
__global__ __launch_bounds__(256)
void prep_kernel(const float* __restrict__ x, const float* __restrict__ Wq,
                 const float* __restrict__ Wk, const float* __restrict__ Wv,
                 const float* __restrict__ Wo, ushort_t* __restrict__ xb,
                 ushort_t* __restrict__ WqkvT, ushort_t* __restrict__ WoT)
{
    __shared__ float T[32][33];
    int blk = blockIdx.x;
    if (blk < 4096) {                      // cast: 4096*256*4 = 4M elements
        const int i = blk * 256 + threadIdx.x;
        float4 v = ((const float4*)x)[i];
        uint2 o;
        o.x = pk2h(v.x, v.y);
        o.y = pk2h(v.z, v.w);
        ((uint2*)xb)[i] = o;
        return;
    }
    blk -= 4096;
    const float* src; ushort_t* dst; int N, bx, by;
    if (blk < 1024)      { src = Wq; dst = WqkvT;                            N = D_MODEL; bx = blk & 31; by = blk >> 5; }
    else if (blk < 1280) { blk -= 1024; src = Wk; dst = WqkvT + (size_t)1024 * D_MODEL; N = KVDIM; bx = blk & 7; by = blk >> 3; }
    else if (blk < 1536) { blk -= 1280; src = Wv; dst = WqkvT + (size_t)1280 * D_MODEL; N = KVDIM; bx = blk & 7; by = blk >> 3; }
    else                 { blk -= 1536; src = Wo; dst = WoT;                 N = D_MODEL; bx = blk & 31; by = blk >> 5; }
    const int tx = threadIdx.x & 31, ty = threadIdx.x >> 5;
    const int n0 = bx * 32, k0 = by * 32;
#pragma unroll
    for (int i = 0; i < 4; i++)
        T[ty + i * 8][tx] = src[(size_t)(k0 + ty + i * 8) * N + n0 + tx];
    __syncthreads();
#pragma unroll
    for (int i = 0; i < 4; i++)
        dst[(size_t)(n0 + ty + i * 8) * D_MODEL + k0 + tx] = f2h(T[tx][ty + i * 8]);
}

// ---------------------------------------------------------------------------
// V transpose: QKVh (f16) cols [1280,1536) per batch -> Vt f16 [(b*256+d)][2048]
// ---------------------------------------------------------------------------
__global__ __launch_bounds__(256)
void vtrans_kernel(const ushort_t* __restrict__ QKVh, ushort_t* __restrict__ Vt)
{
    __shared__ ushort_t T[32][34];
    const int tx = threadIdx.x & 31, ty = threadIdx.x >> 5;
    const int n0 = blockIdx.x * 32, d0 = blockIdx.y * 32, b = blockIdx.z;
#pragma unroll
    for (int i = 0; i < 4; i++)
        T[ty + i * 8][tx] =
            QKVh[(size_t)(b * NN + n0 + ty + i * 8) * QKVN + 1280 + d0 + tx];
    __syncthreads();
#pragma unroll
    for (int i = 0; i < 4; i++)
        Vt[(size_t)(b * 256 + d0 + ty + i * 8) * NN + n0 + tx] = T[tx][ty + i * 8];
}

// ---------------------------------------------------------------------------
// RoPE (f16 in/out) + relayout for Q and K. Q gets 0.125*log2(e) folded in.
// ---------------------------------------------------------------------------
#define NQW (MROWS*NHEADS*32)   // 2,097,152
#define NKW (MROWS*NKV*32)      //   524,288
__global__ __launch_bounds__(256)
void rope_kernel(const ushort_t* __restrict__ QKVh, const float* __restrict__ Cos,
                 const float* __restrict__ Sin, ushort_t* __restrict__ Qb,
                 ushort_t* __restrict__ Kb)
{
    const float SC = 0.125f * 1.44269504f;
    int idx = blockIdx.x * 256 + threadIdx.x;
    if (idx < NQW) {
        const int row = idx >> 9, rem = idx & 511;
        const int h = rem >> 5, j = rem & 31;
        const int b = row >> 11, n = row & (NN - 1);
        const uint_t pr = *(const uint_t*)&QKVh[(size_t)row * QKVN + h * 64 + 2 * j];
        const float e = h2f((ushort_t)pr), o = h2f((ushort_t)(pr >> 16));
        const float c = Cos[n * 32 + j], s = Sin[n * 32 + j];
        ushort_t* dst = Qb + ((size_t)(b * 16 + h) * NN + n) * 64;
        dst[j]      = f2h((e * c - o * s) * SC);
        dst[j + 32] = f2h((e * s + o * c) * SC);
    } else {
        const int i2 = idx - NQW;
        const int row = i2 >> 7, rem = i2 & 127;
        const int h = rem >> 5, j = rem & 31;
        const int b = row >> 11, n = row & (NN - 1);
        const uint_t pr = *(const uint_t*)&QKVh[(size_t)row * QKVN + 1024 + h * 64 + 2 * j];
        const float e = h2f((ushort_t)pr), o = h2f((ushort_t)(pr >> 16));
        const float c = Cos[n * 32 + j], s = Sin[n * 32 + j];
        ushort_t* dst = Kb + ((size_t)(b * 4 + h) * NN + n) * 64;
        dst[j]      = f2h(e * c - o * s);
        dst[j + 32] = f2h(e * s + o * c);
    }
}

// ---------------------------------------------------------------------------
// f16 MFMA GEMM for QKV (f16 out), 128x64 tile, GLDS + XOR swizzle +
// double-buffered LDS, one barrier/iter (round-12 structure).
// ---------------------------------------------------------------------------
__global__ __launch_bounds__(256)
void gemm_qkv(const ushort_t* __restrict__ A, const ushort_t* __restrict__ Bt,
              ushort_t* __restrict__ C, int M, int N, int K)
{
    __shared__ ushort_t As[2][128 * 32];
    __shared__ ushort_t Bs[2][64 * 32];

    const int tid  = threadIdx.x;
    const int wave = tid >> 6, lane = tid & 63;
    const int quad = lane >> 4, l16 = lane & 15;
    const int rowBase = blockIdx.y * 128, colBase = blockIdx.x * 64;
    const int wm = (wave >> 1) * 64, wn = (wave & 1) * 32;

    f32x4 acc[4][2];
    const f32x4 zz = {0.f, 0.f, 0.f, 0.f};
#pragma unroll
    for (int i = 0; i < 4; i++)
#pragma unroll
        for (int j = 0; j < 2; j++) acc[i][j] = zz;

    const int sr = wave * 32 + (lane >> 2);
    const int sc = ((lane & 3) ^ ((lane >> 3) & 3)) * 8;
    const ushort_t* Ag0 = A + (size_t)(rowBase + sr) * K + sc;
    const ushort_t* Ag1 = A + (size_t)(rowBase + sr + 16) * K + sc;
    const int segA0 = (wave * 2 + 0) * 512, segA1 = (wave * 2 + 1) * 512;
    const int br = wave * 16 + (lane >> 2);
    const ushort_t* Bg0 = Bt + (size_t)(colBase + br) * K + sc;
    const int segB = wave * 512;

    const int fcol = (quad ^ ((l16 >> 1) & 3)) * 8;

    GLDS(Ag0, &As[0][segA0]);
    GLDS(Ag1, &As[0][segA1]);
    GLDS(Bg0, &Bs[0][segB]);

    for (int k0 = 0; k0 < K; k0 += 32) {
        const int cur = (k0 >> 5) & 1, nxt = cur ^ 1;
        __syncthreads();
        if (k0 + 32 < K) {
            GLDS(Ag0 + k0 + 32, &As[nxt][segA0]);
            GLDS(Ag1 + k0 + 32, &As[nxt][segA1]);
            GLDS(Bg0 + k0 + 32, &Bs[nxt][segB]);
        }

        h16x8 af[4], bf[2];
#pragma unroll
        for (int mt = 0; mt < 4; mt++)
            af[mt] = *(const h16x8*)&As[cur][(wm + mt * 16 + l16) * 32 + fcol];
#pragma unroll
        for (int nt = 0; nt < 2; nt++)
            bf[nt] = *(const h16x8*)&Bs[cur][(wn + nt * 16 + l16) * 32 + fcol];
#pragma unroll
        for (int mt = 0; mt < 4; mt++)
#pragma unroll
            for (int nt = 0; nt < 2; nt++)
                acc[mt][nt] = MFMAH(af[mt], bf[nt], acc[mt][nt]);
    }

#pragma unroll
    for (int mt = 0; mt < 4; mt++)
#pragma unroll
        for (int nt = 0; nt < 2; nt++) {
            const int row = rowBase + wm + mt * 16 + quad * 4;
            const int col = colBase + wn + nt * 16 + l16;
#pragma unroll
            for (int r = 0; r < 4; r++)
                C[(size_t)(row + r) * N + col] = f2h(acc[mt][nt][r]);
        }
}

// ---------------------------------------------------------------------------
// MFMA flash attention. Round-18 (= r17 with intrinsic spelling fixed):
// r0 structure (2 barriers/tile, single-buffered K/V, NSPLIT=2) with the
// P LDS round-trip ELIMINATED: PV uses K=16 MFMAs (mfma_f32_16x16x16f16)
// whose B-operand layout (k=quad*4+i) matches the QK^T D-layout register
// grouping (keys quad*4+r) -- P stays in registers. Deletes per tile:
// 16 ds_write_b64 + 8 ds_read_b128 + 4 serialized lgkmcnt(0) round-trips
// + the 9KB Ps buffer. Adds: 32 MFMA issues (same FLOPs, K=16) + 16
// ds_read_b64 V-fragment reads (kt-sliced).
// ---------------------------------------------------------------------------
__global__ __launch_bounds__(256)
void attn_mfma(const ushort_t* __restrict__ Qb, const ushort_t* __restrict__ Kb,
               const ushort_t* __restrict__ Vt, ushort_t* __restrict__ Pnum,
               float* __restrict__ Pl)
{
    const int qt = blockIdx.x, h = blockIdx.y;
    const int b = blockIdx.z >> 1, chunk = blockIdx.z & 1;
    const int kvh = h >> 2;
    const int tid = threadIdx.x;
    const int wave = tid >> 6, lane = tid & 63;
    const int quad = lane >> 4, l16 = lane & 15;

    __shared__ ushort_t Ks[64][72];
    __shared__ ushort_t Vs[64][72];

    const int row0 = qt * 256 + wave * 64;
    h16x8 qf[4][2];
#pragma unroll
    for (int mt = 0; mt < 4; mt++) {
        const ushort_t* qp =
            Qb + ((size_t)(b * 16 + h) * NN + row0 + mt * 16 + l16) * 64 + quad * 8;
        qf[mt][0] = *(const h16x8*)qp;
        qf[mt][1] = *(const h16x8*)(qp + 32);
    }

    const ushort_t* kbase = Kb + (size_t)(b * 4 + kvh) * NN * 64;
    const ushort_t* vbase = Vt + (size_t)(b * 256 + kvh * 64) * NN;
    const int key_lo = chunk * (NN / NSPLIT);          // 1024-key chunk
    const int rot = (qt + ((h & 3) << 2)) & 15;

    const int srow = tid >> 2, sseg = (tid & 3) * 8;

    const f32x4 zz = {0.f, 0.f, 0.f, 0.f};
    f32x4 o[4][4];
#pragma unroll
    for (int mt = 0; mt < 4; mt++)
#pragma unroll
        for (int dt = 0; dt < 4; dt++) o[mt][dt] = zz;
    float lacc[4] = {0.f, 0.f, 0.f, 0.f};

    int key0 = key_lo + rot * 64;
    const ushort_t* kp0 = kbase + (size_t)(key0 + srow) * 64 + sseg;
    const ushort_t* vp0 = vbase + (size_t)srow * NN + key0 + sseg;
    uint4 kreg0 = *(const uint4*)kp0;
    uint4 kreg1 = *(const uint4*)(kp0 + 32);
    uint4 vreg0 = *(const uint4*)vp0;
    uint4 vreg1 = *(const uint4*)(vp0 + 32);

    for (int t = 0; t < 16; t++) {
        __syncthreads();
        *(uint4*)&Ks[srow][sseg]      = kreg0;
        *(uint4*)&Ks[srow][sseg + 32] = kreg1;
        *(uint4*)&Vs[srow][sseg]      = vreg0;
        *(uint4*)&Vs[srow][sseg + 32] = vreg1;
        __syncthreads();

        if (t < 15) {
            const int kn = key_lo + ((rot + t + 1) & 15) * 64;
            const ushort_t* kpn = kbase + (size_t)(kn + srow) * 64 + sseg;
            const ushort_t* vpn = vbase + (size_t)srow * NN + kn + sseg;
            kreg0 = *(const uint4*)kpn;
            kreg1 = *(const uint4*)(kpn + 32);
            vreg0 = *(const uint4*)vpn;
            vreg1 = *(const uint4*)(vpn + 32);
        }

        // ---- fused per-kt: S^T = K Q^T -> exp2 -> pack -> PV (K=16, P in regs)
#pragma unroll
        for (int kt = 0; kt < 4; kt++) {
            h16x8 kf0 = *(const h16x8*)&Ks[kt * 16 + l16][quad * 8];
            h16x8 kf1 = *(const h16x8*)&Ks[kt * 16 + l16][32 + quad * 8];
            // V fragments for this kt: A-layout (K=16) = Vt[d][kt*16+quad*4+i]
            h16x4 va[4];
#pragma unroll
            for (int dt = 0; dt < 4; dt++)
                va[dt] = *(const h16x4*)&Vs[dt * 16 + l16][kt * 16 + quad * 4];

            uint2 pb[4];
#pragma unroll
            for (int mt = 0; mt < 4; mt++) {
                f32x4 st = MFMAH(kf0, qf[mt][0], zz);
                st = MFMAH(kf1, qf[mt][1], st);
                const float p0 = exp2f(st[0]);
                const float p1 = exp2f(st[1]);
                const float p2 = exp2f(st[2]);
                const float p3 = exp2f(st[3]);
                lacc[mt] += (p0 + p1) + (p2 + p3);
                pb[mt].x = pk2h(p0, p1);
                pb[mt].y = pk2h(p2, p3);
            }
#pragma unroll
            for (int mt = 0; mt < 4; mt++) {
                const h16x4 pbv = *(const h16x4*)&pb[mt];
#pragma unroll
                for (int dt = 0; dt < 4; dt++)
                    o[mt][dt] = MFMA16(va[dt], pbv, o[mt][dt]);
            }
        }
    }

#pragma unroll
    for (int mt = 0; mt < 4; mt++) {
        lacc[mt] += __shfl_xor(lacc[mt], 16, 64);
        lacc[mt] += __shfl_xor(lacc[mt], 32, 64);
    }

    const size_t task0 = (size_t)(b * 16 + h) * NN + row0;
    ushort_t* np = Pnum + ((size_t)chunk * NTASK + task0) * 64;
#pragma unroll
    for (int mt = 0; mt < 4; mt++) {
        const float inv = 1.0f / lacc[mt];
#pragma unroll
        for (int dt = 0; dt < 4; dt++) {
            f32x4 v = o[mt][dt];
            uint2 pk;
            pk.x = pk2h(v[0] * inv, v[1] * inv);
            pk.y = pk2h(v[2] * inv, v[3] * inv);
            *(uint2*)&np[(size_t)(mt * 16 + l16) * 64 + dt * 16 + quad * 4] = pk;
        }
        if (quad == 0)
            Pl[(size_t)chunk * NTASK + task0 + mt * 16 + l16] = lacc[mt];
    }
}

// ---------------------------------------------------------------------------
// Wo GEMM with FUSED split-K combine: A[r][c] = (l0*ohat0 + l1*ohat1)/(l0+l1)
// computed during A-tile staging (manual ds_write into padded stride-40 LDS,
// 2 barriers/iter); B staged via GLDS + XOR swizzle, double-buffered.
// 128x64 tile, fp32 out. Deletes the combine kernel + Obuf round-trip.
// ---------------------------------------------------------------------------
__global__ __launch_bounds__(256)
void gemm_wo(const ushort_t* __restrict__ Pnum, const float* __restrict__ Pl,
             const ushort_t* __restrict__ WoT, float* __restrict__ C)
{
    __shared__ ushort_t As[2][128 * 40];   // padded rows: conflict-free b128
    __shared__ ushort_t Bs[2][64 * 32];

    const int tid  = threadIdx.x;
    const int wave = tid >> 6, lane = tid & 63;
    const int quad = lane >> 4, l16 = lane & 15;
    const int rowBase = blockIdx.y * 128, colBase = blockIdx.x * 64;
    const int wm = (wave >> 1) * 64, wn = (wave & 1) * 32;

    f32x4 acc[4][2];
    const f32x4 zz = {0.f, 0.f, 0.f, 0.f};
#pragma unroll
    for (int i = 0; i < 4; i++)
#pragma unroll
        for (int j = 0; j < 2; j++) acc[i][j] = zz;

    // A combine-staging: lane handles rows r0, r0+64; 8 cols at c8
    const int r0 = tid >> 2;             // 0..63
    const int c8 = (tid & 3) * 8;
    const int bB = rowBase >> 11;        // batch (scalar: 128 | 2048)
    const int n0 = (rowBase & (NN - 1)) + r0;

    // B staging (GLDS + swizzle)
    const int br = wave * 16 + (lane >> 2);
    const int sc = ((lane & 3) ^ ((lane >> 3) & 3)) * 8;
    const ushort_t* Bg0 = WoT + (size_t)(colBase + br) * D_MODEL + sc;
    const int segB = wave * 512;
    const int fcol = (quad ^ ((l16 >> 1) & 3)) * 8;

    uint4 a0c0, a0c1, a1c0, a1c1;
    float l00, l01, l10, l11;
    // prefetch A inputs for K-slice k0
#define PREFA(k0) { \
        const int h_ = (k0) >> 6; \
        const int d_ = ((k0) & 63) + c8; \
        const size_t t0_ = ((size_t)(bB * 16 + h_) << 11) + n0; \
        const size_t t1_ = t0_ + 64; \
        a0c0 = *(const uint4*)&Pnum[t0_ * 64 + d_]; \
        a0c1 = *(const uint4*)&Pnum[((size_t)NTASK + t0_) * 64 + d_]; \
        a1c0 = *(const uint4*)&Pnum[t1_ * 64 + d_]; \
        a1c1 = *(const uint4*)&Pnum[((size_t)NTASK + t1_) * 64 + d_]; \
        l00 = Pl[t0_]; l01 = Pl[NTASK + t0_]; \
        l10 = Pl[t1_]; l11 = Pl[NTASK + t1_]; \
    }

    PREFA(0);
    GLDS(Bg0, &Bs[0][segB]);

    for (int k0 = 0; k0 < D_MODEL; k0 += 32) {
        const int cur = (k0 >> 5) & 1, nxt = cur ^ 1;
        __syncthreads();     // prev-iter frag reads done; Bs[cur] GLDS drained

        // combine + stage A (two rows)
        {
            const float i0 = 1.f / (l00 + l01), w00 = l00 * i0, w01 = l01 * i0;
            const float i1 = 1.f / (l10 + l11), w10 = l10 * i1, w11 = l11 * i1;
            uint4 o0, o1;
            const uint_t* p0 = (const uint_t*)&a0c0;
            const uint_t* p1 = (const uint_t*)&a0c1;
            const uint_t* q0 = (const uint_t*)&a1c0;
            const uint_t* q1 = (const uint_t*)&a1c1;
            uint_t* po = (uint_t*)&o0;
            uint_t* qo = (uint_t*)&o1;
#pragma unroll
            for (int j = 0; j < 4; j++) {
                fp16x2 u = *(const fp16x2*)&p0[j];
                fp16x2 v = *(const fp16x2*)&p1[j];
                po[j] = pk2h(w00 * (float)u.x + w01 * (float)v.x,
                             w00 * (float)u.y + w01 * (float)v.y);
                fp16x2 s = *(const fp16x2*)&q0[j];
                fp16x2 r = *(const fp16x2*)&q1[j];
                qo[j] = pk2h(w10 * (float)s.x + w11 * (float)r.x,
                             w10 * (float)s.y + w11 * (float)r.y);
            }
            *(uint4*)&As[cur][r0 * 40 + c8]        = o0;
            *(uint4*)&As[cur][(r0 + 64) * 40 + c8] = o1;
        }
        __syncthreads();     // As[cur] visible to all waves

        if (k0 + 32 < D_MODEL) {
            GLDS(Bg0 + k0 + 32, &Bs[nxt][segB]);
            PREFA(k0 + 32);
        }

        h16x8 af[4], bf[2];
#pragma unroll
        for (int mt = 0; mt < 4; mt++)
            af[mt] = *(const h16x8*)&As[cur][(wm + mt * 16 + l16) * 40 + quad * 8];
#pragma unroll
        for (int nt = 0; nt < 2; nt++)
            bf[nt] = *(const h16x8*)&Bs[cur][(wn + nt * 16 + l16) * 32 + fcol];
#pragma unroll
        for (int mt = 0; mt < 4; mt++)
#pragma unroll
            for (int nt = 0; nt < 2; nt++)
                acc[mt][nt] = MFMAH(af[mt], bf[nt], acc[mt][nt]);
    }
#undef PREFA

#pragma unroll
    for (int mt = 0; mt < 4; mt++)
#pragma unroll
        for (int nt = 0; nt < 2; nt++) {
            const int row = rowBase + wm + mt * 16 + quad * 4;
            const int col = colBase + wn + nt * 16 + l16;
#pragma unroll
            for (int r = 0; r < 4; r++)
                C[(size_t)(row + r) * D_MODEL + col] = acc[mt][nt][r];
        }
}

// ---------------------------------------------------------------------------
extern "C" void kernel_launch(void* const* d_in, const int* in_sizes, int n_in,
                              void* d_out, int out_size, void* d_ws, size_t ws_size,
                              hipStream_t stream)
{
    const float* x    = (const float*)d_in[0];
    const float* cosp = (const float*)d_in[1];
    const float* sinp = (const float*)d_in[2];
    const float* Wq   = (const float*)d_in[3];
    const float* Wk   = (const float*)d_in[4];
    const float* Wv   = (const float*)d_in[5];
    const float* Wo   = (const float*)d_in[6];

    char* w = (char*)d_ws;
    ushort_t* xb     = (ushort_t*)w;                       w += (size_t)MROWS * D_MODEL * 2;
    ushort_t* WqkvT  = (ushort_t*)w;                       w += (size_t)QKVN * D_MODEL * 2;
    ushort_t* WoT    = (ushort_t*)w;                       w += (size_t)D_MODEL * D_MODEL * 2;
    ushort_t* QKVh   = (ushort_t*)w;                       w += (size_t)MROWS * QKVN * 2;
    ushort_t* Qbuf   = (ushort_t*)w;                       w += (size_t)MROWS * D_MODEL * 2;
    ushort_t* Kbuf   = (ushort_t*)w;                       w += (size_t)MROWS * KVDIM * 2;
    ushort_t* Vt     = (ushort_t*)w;                       w += (size_t)MROWS * KVDIM * 2;
    ushort_t* Pnum   = (ushort_t*)w;                       w += (size_t)NSPLIT * NTASK * 64 * 2;
    float*    Pl     = (float*)w;

    // --- fused prep (cast + 4 transposes): 1 dispatch
    prep_kernel<<<6656, 256, 0, stream>>>(x, Wq, Wk, Wv, Wo, xb, WqkvT, WoT);

    // --- fused QKV projection (f16 out)
    gemm_qkv<<<dim3(QKVN / 64, MROWS / 128), 256, 0, stream>>>(
        xb, WqkvT, QKVh, MROWS, QKVN, D_MODEL);

    // --- rope + relayout (Q,K), V transpose
    rope_kernel<<<(NQW + NKW) / 256, 256, 0, stream>>>(QKVh, cosp, sinp, Qbuf, Kbuf);
    vtrans_kernel<<<dim3(NN / 32, KVDIM / 32, BB), 256, 0, stream>>>(QKVh, Vt);

    // --- attention (split-K x2, P kept in registers via K=16 PV MFMAs)
    attn_mfma<<<dim3(NN / 256, NHEADS, BB * NSPLIT), 256, 0, stream>>>(
        Qbuf, Kbuf, Vt, Pnum, Pl);

    // --- output projection with fused combine (fp32 out)
    gemm_wo<<<dim3(D_MODEL / 64, MROWS / 128), 256, 0, stream>>>(
        Pnum, Pl, WoT, (float*)d_out);
}

// Round 7
// 205.641 us; speedup vs baseline: 1.1463x; 1.0276x over previous
//
#include <hip/hip_runtime.h>
#include <math.h>

#define D_MODEL 1024
#define NHEADS  16
#define NKV     4
#define HDIM    64
#define KVDIM   256
#define BB      2
#define NN      2048
#define MROWS   (BB*NN)        // 4096
#define QKVN    1536           // 1024 + 256 + 256
#define NTASK   (MROWS*NHEADS) // 65536
#define NSPLIT  2

typedef unsigned short ushort_t;
typedef unsigned int uint_t;
typedef float    f32x4 __attribute__((ext_vector_type(4)));
typedef _Float16 h16x8 __attribute__((ext_vector_type(8)));
typedef _Float16 h16x4 __attribute__((ext_vector_type(4)));
typedef __fp16   fp16x2 __attribute__((ext_vector_type(2)));

#define MFMAH(A,B,C)  __builtin_amdgcn_mfma_f32_16x16x32_f16((A),(B),(C),0,0,0)
// NOTE spelling: carried-forward GCN-era intrinsic has NO underscore before f16
#define MFMA16(A,B,C) __builtin_amdgcn_mfma_f32_16x16x16f16((A),(B),(C),0,0,0)
// raw v_exp_f32 (1 instr) -- libm exp2f carries a ~6-instr denormal fixup
#define EXP2(x) __builtin_amdgcn_exp2f(x)

// async global->LDS, 16B per lane; LDS dest = wave-uniform base + lane*16
#define GLDS(gp, lp) __builtin_amdgcn_global_load_lds( \
    (const __attribute__((address_space(1))) void*)(gp), \
    (__attribute__((address_space(3))) void*)(lp), 16, 0, 0)

__device__ __forceinline__ ushort_t f2h(float f) {
    _Float16 h = (_Float16)f;
    return *(ushort_t*)&h;
}
__device__ __forceinline__ float h2f(ushort_t u) {
    return (float)(*(const _Float16*)&u);
}
// two fp32 -> packed f16x2, single v_cvt_pkrtz_f16_f32
__device__ __forceinline__ uint_t pk2h(float a, float b) {
    fp16x2 v = __builtin_amdgcn_cvt_pkrtz(a, b);
    return *(uint_t*)&v;
}

// ---------------------------------------------------------------------------
// Fused prep: cast x->f16 (blocks [0,4096)) + 4 weight transpose-casts
// (blocks [4096,6656)). One dispatch instead of five.
// ---------------------------------------------------------------------------
__global__ __launch_bounds__(256)
void prep_kernel(const float* __restrict__ x, const float* __restrict__ Wq,
                 const float* __restrict__ Wk, const float* __restrict__ Wv,
                 const float* __restrict__ Wo, ushort_t* __restrict__ xb,
                 ushort_t* __restrict__ WqkvT, ushort_t* __restrict__ WoT)
{
    __shared__ float T[32][33];
    int blk = blockIdx.x;
    if (blk < 4096) {                      // cast: 4096*256*4 = 4M elements
        const int i = blk * 256 + threadIdx.x;
        float4 v = ((const float4*)x)[i];
        uint2 o;
        o.x = pk2h(v.x, v.y);
        o.y = pk2h(v.z, v.w);
        ((uint2*)xb)[i] = o;
        return;
    }
    blk -= 4096;
    const float* src; ushort_t* dst; int N, bx, by;
    if (blk < 1024)      { src = Wq; dst = WqkvT;                            N = D_MODEL; bx = blk & 31; by = blk >> 5; }
    else if (blk < 1280) { blk -= 1024; src = Wk; dst = WqkvT + (size_t)1024 * D_MODEL; N = KVDIM; bx = blk & 7; by = blk >> 3; }
    else if (blk < 1536) { blk -= 1280; src = Wv; dst = WqkvT + (size_t)1280 * D_MODEL; N = KVDIM; bx = blk & 7; by = blk >> 3; }
    else                 { blk -= 1536; src = Wo; dst = WoT;                 N = D_MODEL; bx = blk & 31; by = blk >> 5; }
    const int tx = threadIdx.x & 31, ty = threadIdx.x >> 5;
    const int n0 = bx * 32, k0 = by * 32;
#pragma unroll
    for (int i = 0; i < 4; i++)
        T[ty + i * 8][tx] = src[(size_t)(k0 + ty + i * 8) * N + n0 + tx];
    __syncthreads();
#pragma unroll
    for (int i = 0; i < 4; i++)
        dst[(size_t)(n0 + ty + i * 8) * D_MODEL + k0 + tx] = f2h(T[tx][ty + i * 8]);
}

// ---------------------------------------------------------------------------
// V transpose: QKVh (f16) cols [1280,1536) per batch -> Vt f16 [(b*256+d)][2048]
// ---------------------------------------------------------------------------
__global__ __launch_bounds__(256)
void vtrans_kernel(const ushort_t* __restrict__ QKVh, ushort_t* __restrict__ Vt)
{
    __shared__ ushort_t T[32][34];
    const int tx = threadIdx.x & 31, ty = threadIdx.x >> 5;
    const int n0 = blockIdx.x * 32, d0 = blockIdx.y * 32, b = blockIdx.z;
#pragma unroll
    for (int i = 0; i < 4; i++)
        T[ty + i * 8][tx] =
            QKVh[(size_t)(b * NN + n0 + ty + i * 8) * QKVN + 1280 + d0 + tx];
    __syncthreads();
#pragma unroll
    for (int i = 0; i < 4; i++)
        Vt[(size_t)(b * 256 + d0 + ty + i * 8) * NN + n0 + tx] = T[tx][ty + i * 8];
}

// ---------------------------------------------------------------------------
// RoPE (f16 in/out) + relayout for Q and K. Q gets 0.125*log2(e) folded in.
// ---------------------------------------------------------------------------
#define NQW (MROWS*NHEADS*32)   // 2,097,152
#define NKW (MROWS*NKV*32)      //   524,288
__global__ __launch_bounds__(256)
void rope_kernel(const ushort_t* __restrict__ QKVh, const float* __restrict__ Cos,
                 const float* __restrict__ Sin, ushort_t* __restrict__ Qb,
                 ushort_t* __restrict__ Kb)
{
    const float SC = 0.125f * 1.44269504f;
    int idx = blockIdx.x * 256 + threadIdx.x;
    if (idx < NQW) {
        const int row = idx >> 9, rem = idx & 511;
        const int h = rem >> 5, j = rem & 31;
        const int b = row >> 11, n = row & (NN - 1);
        const uint_t pr = *(const uint_t*)&QKVh[(size_t)row * QKVN + h * 64 + 2 * j];
        const float e = h2f((ushort_t)pr), o = h2f((ushort_t)(pr >> 16));
        const float c = Cos[n * 32 + j], s = Sin[n * 32 + j];
        ushort_t* dst = Qb + ((size_t)(b * 16 + h) * NN + n) * 64;
        dst[j]      = f2h((e * c - o * s) * SC);
        dst[j + 32] = f2h((e * s + o * c) * SC);
    } else {
        const int i2 = idx - NQW;
        const int row = i2 >> 7, rem = i2 & 127;
        const int h = rem >> 5, j = rem & 31;
        const int b = row >> 11, n = row & (NN - 1);
        const uint_t pr = *(const uint_t*)&QKVh[(size_t)row * QKVN + 1024 + h * 64 + 2 * j];
        const float e = h2f((ushort_t)pr), o = h2f((ushort_t)(pr >> 16));
        const float c = Cos[n * 32 + j], s = Sin[n * 32 + j];
        ushort_t* dst = Kb + ((size_t)(b * 4 + h) * NN + n) * 64;
        dst[j]      = f2h(e * c - o * s);
        dst[j + 32] = f2h(e * s + o * c);
    }
}

// ---------------------------------------------------------------------------
// f16 MFMA GEMM for QKV (f16 out), 128x64 tile, GLDS + XOR swizzle +
// double-buffered LDS, one barrier/iter (round-12 structure).
// ---------------------------------------------------------------------------
__global__ __launch_bounds__(256)
void gemm_qkv(const ushort_t* __restrict__ A, const ushort_t* __restrict__ Bt,
              ushort_t* __restrict__ C, int M, int N, int K)
{
    __shared__ ushort_t As[2][128 * 32];
    __shared__ ushort_t Bs[2][64 * 32];

    const int tid  = threadIdx.x;
    const int wave = tid >> 6, lane = tid & 63;
    const int quad = lane >> 4, l16 = lane & 15;
    const int rowBase = blockIdx.y * 128, colBase = blockIdx.x * 64;
    const int wm = (wave >> 1) * 64, wn = (wave & 1) * 32;

    f32x4 acc[4][2];
    const f32x4 zz = {0.f, 0.f, 0.f, 0.f};
#pragma unroll
    for (int i = 0; i < 4; i++)
#pragma unroll
        for (int j = 0; j < 2; j++) acc[i][j] = zz;

    const int sr = wave * 32 + (lane >> 2);
    const int sc = ((lane & 3) ^ ((lane >> 3) & 3)) * 8;
    const ushort_t* Ag0 = A + (size_t)(rowBase + sr) * K + sc;
    const ushort_t* Ag1 = A + (size_t)(rowBase + sr + 16) * K + sc;
    const int segA0 = (wave * 2 + 0) * 512, segA1 = (wave * 2 + 1) * 512;
    const int br = wave * 16 + (lane >> 2);
    const ushort_t* Bg0 = Bt + (size_t)(colBase + br) * K + sc;
    const int segB = wave * 512;

    const int fcol = (quad ^ ((l16 >> 1) & 3)) * 8;

    GLDS(Ag0, &As[0][segA0]);
    GLDS(Ag1, &As[0][segA1]);
    GLDS(Bg0, &Bs[0][segB]);

    for (int k0 = 0; k0 < K; k0 += 32) {
        const int cur = (k0 >> 5) & 1, nxt = cur ^ 1;
        __syncthreads();
        if (k0 + 32 < K) {
            GLDS(Ag0 + k0 + 32, &As[nxt][segA0]);
            GLDS(Ag1 + k0 + 32, &As[nxt][segA1]);
            GLDS(Bg0 + k0 + 32, &Bs[nxt][segB]);
        }

        h16x8 af[4], bf[2];
#pragma unroll
        for (int mt = 0; mt < 4; mt++)
            af[mt] = *(const h16x8*)&As[cur][(wm + mt * 16 + l16) * 32 + fcol];
#pragma unroll
        for (int nt = 0; nt < 2; nt++)
            bf[nt] = *(const h16x8*)&Bs[cur][(wn + nt * 16 + l16) * 32 + fcol];
#pragma unroll
        for (int mt = 0; mt < 4; mt++)
#pragma unroll
            for (int nt = 0; nt < 2; nt++)
                acc[mt][nt] = MFMAH(af[mt], bf[nt], acc[mt][nt]);
    }

#pragma unroll
    for (int mt = 0; mt < 4; mt++)
#pragma unroll
        for (int nt = 0; nt < 2; nt++) {
            const int row = rowBase + wm + mt * 16 + quad * 4;
            const int col = colBase + wn + nt * 16 + l16;
#pragma unroll
            for (int r = 0; r < 4; r++)
                C[(size_t)(row + r) * N + col] = f2h(acc[mt][nt][r]);
        }
}

// ---------------------------------------------------------------------------
// MFMA flash attention. Round-19 (= r18 with ONE change): exp2f ->
// __builtin_amdgcn_exp2f. r18's counters showed VALUBusy 58.5% dominated by
// the libm exp2 denormal-fixup wrapper (~6 VALU instrs per call, 64 calls/
// tile); raw v_exp_f32 is 1 instr and denormal-flush is harmless for
// softmax. Keeps: K=16 in-register PV (layout verified by r18 pass),
// 2 barriers/tile, single-buffered K/V, NSPLIT=2.
// ---------------------------------------------------------------------------
__global__ __launch_bounds__(256)
void attn_mfma(const ushort_t* __restrict__ Qb, const ushort_t* __restrict__ Kb,
               const ushort_t* __restrict__ Vt, ushort_t* __restrict__ Pnum,
               float* __restrict__ Pl)
{
    const int qt = blockIdx.x, h = blockIdx.y;
    const int b = blockIdx.z >> 1, chunk = blockIdx.z & 1;
    const int kvh = h >> 2;
    const int tid = threadIdx.x;
    const int wave = tid >> 6, lane = tid & 63;
    const int quad = lane >> 4, l16 = lane & 15;

    __shared__ ushort_t Ks[64][72];
    __shared__ ushort_t Vs[64][72];

    const int row0 = qt * 256 + wave * 64;
    h16x8 qf[4][2];
#pragma unroll
    for (int mt = 0; mt < 4; mt++) {
        const ushort_t* qp =
            Qb + ((size_t)(b * 16 + h) * NN + row0 + mt * 16 + l16) * 64 + quad * 8;
        qf[mt][0] = *(const h16x8*)qp;
        qf[mt][1] = *(const h16x8*)(qp + 32);
    }

    const ushort_t* kbase = Kb + (size_t)(b * 4 + kvh) * NN * 64;
    const ushort_t* vbase = Vt + (size_t)(b * 256 + kvh * 64) * NN;
    const int key_lo = chunk * (NN / NSPLIT);          // 1024-key chunk
    const int rot = (qt + ((h & 3) << 2)) & 15;

    const int srow = tid >> 2, sseg = (tid & 3) * 8;

    const f32x4 zz = {0.f, 0.f, 0.f, 0.f};
    f32x4 o[4][4];
#pragma unroll
    for (int mt = 0; mt < 4; mt++)
#pragma unroll
        for (int dt = 0; dt < 4; dt++) o[mt][dt] = zz;
    float lacc[4] = {0.f, 0.f, 0.f, 0.f};

    int key0 = key_lo + rot * 64;
    const ushort_t* kp0 = kbase + (size_t)(key0 + srow) * 64 + sseg;
    const ushort_t* vp0 = vbase + (size_t)srow * NN + key0 + sseg;
    uint4 kreg0 = *(const uint4*)kp0;
    uint4 kreg1 = *(const uint4*)(kp0 + 32);
    uint4 vreg0 = *(const uint4*)vp0;
    uint4 vreg1 = *(const uint4*)(vp0 + 32);

    for (int t = 0; t < 16; t++) {
        __syncthreads();
        *(uint4*)&Ks[srow][sseg]      = kreg0;
        *(uint4*)&Ks[srow][sseg + 32] = kreg1;
        *(uint4*)&Vs[srow][sseg]      = vreg0;
        *(uint4*)&Vs[srow][sseg + 32] = vreg1;
        __syncthreads();

        if (t < 15) {
            const int kn = key_lo + ((rot + t + 1) & 15) * 64;
            const ushort_t* kpn = kbase + (size_t)(kn + srow) * 64 + sseg;
            const ushort_t* vpn = vbase + (size_t)srow * NN + kn + sseg;
            kreg0 = *(const uint4*)kpn;
            kreg1 = *(const uint4*)(kpn + 32);
            vreg0 = *(const uint4*)vpn;
            vreg1 = *(const uint4*)(vpn + 32);
        }

        // ---- fused per-kt: S^T = K Q^T -> exp2 -> pack -> PV (K=16, P in regs)
#pragma unroll
        for (int kt = 0; kt < 4; kt++) {
            h16x8 kf0 = *(const h16x8*)&Ks[kt * 16 + l16][quad * 8];
            h16x8 kf1 = *(const h16x8*)&Ks[kt * 16 + l16][32 + quad * 8];
            // V fragments for this kt: A-layout (K=16) = Vt[d][kt*16+quad*4+i]
            h16x4 va[4];
#pragma unroll
            for (int dt = 0; dt < 4; dt++)
                va[dt] = *(const h16x4*)&Vs[dt * 16 + l16][kt * 16 + quad * 4];

            uint2 pb[4];
#pragma unroll
            for (int mt = 0; mt < 4; mt++) {
                f32x4 st = MFMAH(kf0, qf[mt][0], zz);
                st = MFMAH(kf1, qf[mt][1], st);
                const float p0 = EXP2(st[0]);
                const float p1 = EXP2(st[1]);
                const float p2 = EXP2(st[2]);
                const float p3 = EXP2(st[3]);
                lacc[mt] += (p0 + p1) + (p2 + p3);
                pb[mt].x = pk2h(p0, p1);
                pb[mt].y = pk2h(p2, p3);
            }
#pragma unroll
            for (int mt = 0; mt < 4; mt++) {
                const h16x4 pbv = *(const h16x4*)&pb[mt];
#pragma unroll
                for (int dt = 0; dt < 4; dt++)
                    o[mt][dt] = MFMA16(va[dt], pbv, o[mt][dt]);
            }
        }
    }

#pragma unroll
    for (int mt = 0; mt < 4; mt++) {
        lacc[mt] += __shfl_xor(lacc[mt], 16, 64);
        lacc[mt] += __shfl_xor(lacc[mt], 32, 64);
    }

    const size_t task0 = (size_t)(b * 16 + h) * NN + row0;
    ushort_t* np = Pnum + ((size_t)chunk * NTASK + task0) * 64;
#pragma unroll
    for (int mt = 0; mt < 4; mt++) {
        const float inv = 1.0f / lacc[mt];
#pragma unroll
        for (int dt = 0; dt < 4; dt++) {
            f32x4 v = o[mt][dt];
            uint2 pk;
            pk.x = pk2h(v[0] * inv, v[1] * inv);
            pk.y = pk2h(v[2] * inv, v[3] * inv);
            *(uint2*)&np[(size_t)(mt * 16 + l16) * 64 + dt * 16 + quad * 4] = pk;
        }
        if (quad == 0)
            Pl[(size_t)chunk * NTASK + task0 + mt * 16 + l16] = lacc[mt];
    }
}

// ---------------------------------------------------------------------------
// Wo GEMM with FUSED split-K combine: A[r][c] = (l0*ohat0 + l1*ohat1)/(l0+l1)
// computed during A-tile staging (manual ds_write into padded stride-40 LDS,
// 2 barriers/iter); B staged via GLDS + XOR swizzle, double-buffered.
// 128x64 tile, fp32 out. Deletes the combine kernel + Obuf round-trip.
// ---------------------------------------------------------------------------
__global__ __launch_bounds__(256)
void gemm_wo(const ushort_t* __restrict__ Pnum, const float* __restrict__ Pl,
             const ushort_t* __restrict__ WoT, float* __restrict__ C)
{
    __shared__ ushort_t As[2][128 * 40];   // padded rows: conflict-free b128
    __shared__ ushort_t Bs[2][64 * 32];

    const int tid  = threadIdx.x;
    const int wave = tid >> 6, lane = tid & 63;
    const int quad = lane >> 4, l16 = lane & 15;
    const int rowBase = blockIdx.y * 128, colBase = blockIdx.x * 64;
    const int wm = (wave >> 1) * 64, wn = (wave & 1) * 32;

    f32x4 acc[4][2];
    const f32x4 zz = {0.f, 0.f, 0.f, 0.f};
#pragma unroll
    for (int i = 0; i < 4; i++)
#pragma unroll
        for (int j = 0; j < 2; j++) acc[i][j] = zz;

    // A combine-staging: lane handles rows r0, r0+64; 8 cols at c8
    const int r0 = tid >> 2;             // 0..63
    const int c8 = (tid & 3) * 8;
    const int bB = rowBase >> 11;        // batch (scalar: 128 | 2048)
    const int n0 = (rowBase & (NN - 1)) + r0;

    // B staging (GLDS + swizzle)
    const int br = wave * 16 + (lane >> 2);
    const int sc = ((lane & 3) ^ ((lane >> 3) & 3)) * 8;
    const ushort_t* Bg0 = WoT + (size_t)(colBase + br) * D_MODEL + sc;
    const int segB = wave * 512;
    const int fcol = (quad ^ ((l16 >> 1) & 3)) * 8;

    uint4 a0c0, a0c1, a1c0, a1c1;
    float l00, l01, l10, l11;
    // prefetch A inputs for K-slice k0
#define PREFA(k0) { \
        const int h_ = (k0) >> 6; \
        const int d_ = ((k0) & 63) + c8; \
        const size_t t0_ = ((size_t)(bB * 16 + h_) << 11) + n0; \
        const size_t t1_ = t0_ + 64; \
        a0c0 = *(const uint4*)&Pnum[t0_ * 64 + d_]; \
        a0c1 = *(const uint4*)&Pnum[((size_t)NTASK + t0_) * 64 + d_]; \
        a1c0 = *(const uint4*)&Pnum[t1_ * 64 + d_]; \
        a1c1 = *(const uint4*)&Pnum[((size_t)NTASK + t1_) * 64 + d_]; \
        l00 = Pl[t0_]; l01 = Pl[NTASK + t0_]; \
        l10 = Pl[t1_]; l11 = Pl[NTASK + t1_]; \
    }

    PREFA(0);
    GLDS(Bg0, &Bs[0][segB]);

    for (int k0 = 0; k0 < D_MODEL; k0 += 32) {
        const int cur = (k0 >> 5) & 1, nxt = cur ^ 1;
        __syncthreads();     // prev-iter frag reads done; Bs[cur] GLDS drained

        // combine + stage A (two rows)
        {
            const float i0 = 1.f / (l00 + l01), w00 = l00 * i0, w01 = l01 * i0;
            const float i1 = 1.f / (l10 + l11), w10 = l10 * i1, w11 = l11 * i1;
            uint4 o0, o1;
            const uint_t* p0 = (const uint_t*)&a0c0;
            const uint_t* p1 = (const uint_t*)&a0c1;
            const uint_t* q0 = (const uint_t*)&a1c0;
            const uint_t* q1 = (const uint_t*)&a1c1;
            uint_t* po = (uint_t*)&o0;
            uint_t* qo = (uint_t*)&o1;
#pragma unroll
            for (int j = 0; j < 4; j++) {
                fp16x2 u = *(const fp16x2*)&p0[j];
                fp16x2 v = *(const fp16x2*)&p1[j];
                po[j] = pk2h(w00 * (float)u.x + w01 * (float)v.x,
                             w00 * (float)u.y + w01 * (float)v.y);
                fp16x2 s = *(const fp16x2*)&q0[j];
                fp16x2 r = *(const fp16x2*)&q1[j];
                qo[j] = pk2h(w10 * (float)s.x + w11 * (float)r.x,
                             w10 * (float)s.y + w11 * (float)r.y);
            }
            *(uint4*)&As[cur][r0 * 40 + c8]        = o0;
            *(uint4*)&As[cur][(r0 + 64) * 40 + c8] = o1;
        }
        __syncthreads();     // As[cur] visible to all waves

        if (k0 + 32 < D_MODEL) {
            GLDS(Bg0 + k0 + 32, &Bs[nxt][segB]);
            PREFA(k0 + 32);
        }

        h16x8 af[4], bf[2];
#pragma unroll
        for (int mt = 0; mt < 4; mt++)
            af[mt] = *(const h16x8*)&As[cur][(wm + mt * 16 + l16) * 40 + quad * 8];
#pragma unroll
        for (int nt = 0; nt < 2; nt++)
            bf[nt] = *(const h16x8*)&Bs[cur][(wn + nt * 16 + l16) * 32 + fcol];
#pragma unroll
        for (int mt = 0; mt < 4; mt++)
#pragma unroll
            for (int nt = 0; nt < 2; nt++)
                acc[mt][nt] = MFMAH(af[mt], bf[nt], acc[mt][nt]);
    }
#undef PREFA

#pragma unroll
    for (int mt = 0; mt < 4; mt++)
#pragma unroll
        for (int nt = 0; nt < 2; nt++) {
            const int row = rowBase + wm + mt * 16 + quad * 4;
            const int col = colBase + wn + nt * 16 + l16;
#pragma unroll
            for (int r = 0; r < 4; r++)
                C[(size_t)(row + r) * D_MODEL + col] = acc[mt][nt][r];
        }
}

// ---------------------------------------------------------------------------
extern "C" void kernel_launch(void* const* d_in, const int* in_sizes, int n_in,
                              void* d_out, int out_size, void* d_ws, size_t ws_size,
                              hipStream_t stream)
{
    const float* x    = (const float*)d_in[0];
    const float* cosp = (const float*)d_in[1];
    const float* sinp = (const float*)d_in[2];
    const float* Wq   = (const float*)d_in[3];
    const float* Wk   = (const float*)d_in[4];
    const float* Wv   = (const float*)d_in[5];
    const float* Wo   = (const float*)d_in[6];

    char* w = (char*)d_ws;
    ushort_t* xb     = (ushort_t*)w;                       w += (size_t)MROWS * D_MODEL * 2;
    ushort_t* WqkvT  = (ushort_t*)w;                       w += (size_t)QKVN * D_MODEL * 2;
    ushort_t* WoT    = (ushort_t*)w;                       w += (size_t)D_MODEL * D_MODEL * 2;
    ushort_t* QKVh   = (ushort_t*)w;                       w += (size_t)MROWS * QKVN * 2;
    ushort_t* Qbuf   = (ushort_t*)w;                       w += (size_t)MROWS * D_MODEL * 2;
    ushort_t* Kbuf   = (ushort_t*)w;                       w += (size_t)MROWS * KVDIM * 2;
    ushort_t* Vt     = (ushort_t*)w;                       w += (size_t)MROWS * KVDIM * 2;
    ushort_t* Pnum   = (ushort_t*)w;                       w += (size_t)NSPLIT * NTASK * 64 * 2;
    float*    Pl     = (float*)w;

    // --- fused prep (cast + 4 transposes): 1 dispatch
    prep_kernel<<<6656, 256, 0, stream>>>(x, Wq, Wk, Wv, Wo, xb, WqkvT, WoT);

    // --- fused QKV projection (f16 out)
    gemm_qkv<<<dim3(QKVN / 64, MROWS / 128), 256, 0, stream>>>(
        xb, WqkvT, QKVh, MROWS, QKVN, D_MODEL);

    // --- rope + relayout (Q,K), V transpose
    rope_kernel<<<(NQW + NKW) / 256, 256, 0, stream>>>(QKVh, cosp, sinp, Qbuf, Kbuf);
    vtrans_kernel<<<dim3(NN / 32, KVDIM / 32, BB), 256, 0, stream>>>(QKVh, Vt);

    // --- attention (split-K x2, P in registers, raw v_exp_f32)
    attn_mfma<<<dim3(NN / 256, NHEADS, BB * NSPLIT), 256, 0, stream>>>(
        Qbuf, Kbuf, Vt, Pnum, Pl);

    // --- output projection with fused combine (fp32 out)
    gemm_wo<<<dim3(D_MODEL / 64, MROWS / 128), 256, 0, stream>>>(
        Pnum, Pl, WoT, (float*)d_out);
}

// Round 8
// 193.980 us; speedup vs baseline: 1.2152x; 1.0601x over previous
//
#include <hip/hip_runtime.h>
#include <math.h>

#define D_MODEL 1024
#define NHEADS  16
#define NKV     4
#define HDIM    64
#define KVDIM   256
#define BB      2
#define NN      2048
#define MROWS   (BB*NN)        // 4096
#define QKVN    1536           // 1024 + 256 + 256
#define NTASK   (MROWS*NHEADS) // 65536
#define NSPLIT  2
#define KVBLK   128
#define NTILE   ((NN/NSPLIT)/KVBLK)   // 8

typedef unsigned short ushort_t;
typedef unsigned int uint_t;
typedef float    f32x4 __attribute__((ext_vector_type(4)));
typedef _Float16 h16x8 __attribute__((ext_vector_type(8)));
typedef _Float16 h16x4 __attribute__((ext_vector_type(4)));
typedef __fp16   fp16x2 __attribute__((ext_vector_type(2)));

#define MFMAH(A,B,C)  __builtin_amdgcn_mfma_f32_16x16x32_f16((A),(B),(C),0,0,0)
// NOTE spelling: carried-forward GCN-era intrinsic has NO underscore before f16
#define MFMA16(A,B,C) __builtin_amdgcn_mfma_f32_16x16x16f16((A),(B),(C),0,0,0)
// raw v_exp_f32 (1 instr) -- libm exp2f carries a ~6-instr denormal fixup
#define EXP2(x) __builtin_amdgcn_exp2f(x)

// async global->LDS, 16B per lane; LDS dest = wave-uniform base + lane*16
#define GLDS(gp, lp) __builtin_amdgcn_global_load_lds( \
    (const __attribute__((address_space(1))) void*)(gp), \
    (__attribute__((address_space(3))) void*)(lp), 16, 0, 0)

__device__ __forceinline__ ushort_t f2h(float f) {
    _Float16 h = (_Float16)f;
    return *(ushort_t*)&h;
}
__device__ __forceinline__ float h2f(ushort_t u) {
    return (float)(*(const _Float16*)&u);
}
// two fp32 -> packed f16x2, single v_cvt_pkrtz_f16_f32
__device__ __forceinline__ uint_t pk2h(float a, float b) {
    fp16x2 v = __builtin_amdgcn_cvt_pkrtz(a, b);
    return *(uint_t*)&v;
}

// ---------------------------------------------------------------------------
// Fused prep: cast x->f16 (blocks [0,4096)) + 4 weight transpose-casts
// (blocks [4096,6656)). One dispatch instead of five.
// ---------------------------------------------------------------------------
__global__ __launch_bounds__(256)
void prep_kernel(const float* __restrict__ x, const float* __restrict__ Wq,
                 const float* __restrict__ Wk, const float* __restrict__ Wv,
                 const float* __restrict__ Wo, ushort_t* __restrict__ xb,
                 ushort_t* __restrict__ WqkvT, ushort_t* __restrict__ WoT)
{
    __shared__ float T[32][33];
    int blk = blockIdx.x;
    if (blk < 4096) {                      // cast: 4096*256*4 = 4M elements
        const int i = blk * 256 + threadIdx.x;
        float4 v = ((const float4*)x)[i];
        uint2 o;
        o.x = pk2h(v.x, v.y);
        o.y = pk2h(v.z, v.w);
        ((uint2*)xb)[i] = o;
        return;
    }
    blk -= 4096;
    const float* src; ushort_t* dst; int N, bx, by;
    if (blk < 1024)      { src = Wq; dst = WqkvT;                            N = D_MODEL; bx = blk & 31; by = blk >> 5; }
    else if (blk < 1280) { blk -= 1024; src = Wk; dst = WqkvT + (size_t)1024 * D_MODEL; N = KVDIM; bx = blk & 7; by = blk >> 3; }
    else if (blk < 1536) { blk -= 1280; src = Wv; dst = WqkvT + (size_t)1280 * D_MODEL; N = KVDIM; bx = blk & 7; by = blk >> 3; }
    else                 { blk -= 1536; src = Wo; dst = WoT;                 N = D_MODEL; bx = blk & 31; by = blk >> 5; }
    const int tx = threadIdx.x & 31, ty = threadIdx.x >> 5;
    const int n0 = bx * 32, k0 = by * 32;
#pragma unroll
    for (int i = 0; i < 4; i++)
        T[ty + i * 8][tx] = src[(size_t)(k0 + ty + i * 8) * N + n0 + tx];
    __syncthreads();
#pragma unroll
    for (int i = 0; i < 4; i++)
        dst[(size_t)(n0 + ty + i * 8) * D_MODEL + k0 + tx] = f2h(T[tx][ty + i * 8]);
}

// ---------------------------------------------------------------------------
// Fused RoPE (f16 in/out, Q scale folded) + V transpose. One dispatch.
// Blocks [0, ROPEBLKS): rope; blocks [ROPEBLKS, +1024): vtrans.
// ---------------------------------------------------------------------------
#define NQW (MROWS*NHEADS*32)   // 2,097,152
#define NKW (MROWS*NKV*32)      //   524,288
#define ROPEBLKS ((NQW + NKW) / 256)   // 10240
__global__ __launch_bounds__(256)
void ropevt_kernel(const ushort_t* __restrict__ QKVh, const float* __restrict__ Cos,
                   const float* __restrict__ Sin, ushort_t* __restrict__ Qb,
                   ushort_t* __restrict__ Kb, ushort_t* __restrict__ Vt)
{
    __shared__ ushort_t T[32][34];
    if (blockIdx.x >= ROPEBLKS) {
        const int blk2 = blockIdx.x - ROPEBLKS;
        const int bx = blk2 & 63, by = (blk2 >> 6) & 7, b = blk2 >> 9;
        const int tx = threadIdx.x & 31, ty = threadIdx.x >> 5;
        const int n0 = bx * 32, d0 = by * 32;
#pragma unroll
        for (int i = 0; i < 4; i++)
            T[ty + i * 8][tx] =
                QKVh[(size_t)(b * NN + n0 + ty + i * 8) * QKVN + 1280 + d0 + tx];
        __syncthreads();
#pragma unroll
        for (int i = 0; i < 4; i++)
            Vt[(size_t)(b * 256 + d0 + ty + i * 8) * NN + n0 + tx] = T[tx][ty + i * 8];
        return;
    }
    const float SC = 0.125f * 1.44269504f;
    int idx = blockIdx.x * 256 + threadIdx.x;
    if (idx < NQW) {
        const int row = idx >> 9, rem = idx & 511;
        const int h = rem >> 5, j = rem & 31;
        const int b = row >> 11, n = row & (NN - 1);
        const uint_t pr = *(const uint_t*)&QKVh[(size_t)row * QKVN + h * 64 + 2 * j];
        const float e = h2f((ushort_t)pr), o = h2f((ushort_t)(pr >> 16));
        const float c = Cos[n * 32 + j], s = Sin[n * 32 + j];
        ushort_t* dst = Qb + ((size_t)(b * 16 + h) * NN + n) * 64;
        dst[j]      = f2h((e * c - o * s) * SC);
        dst[j + 32] = f2h((e * s + o * c) * SC);
    } else {
        const int i2 = idx - NQW;
        const int row = i2 >> 7, rem = i2 & 127;
        const int h = rem >> 5, j = rem & 31;
        const int b = row >> 11, n = row & (NN - 1);
        const uint_t pr = *(const uint_t*)&QKVh[(size_t)row * QKVN + 1024 + h * 64 + 2 * j];
        const float e = h2f((ushort_t)pr), o = h2f((ushort_t)(pr >> 16));
        const float c = Cos[n * 32 + j], s = Sin[n * 32 + j];
        ushort_t* dst = Kb + ((size_t)(b * 4 + h) * NN + n) * 64;
        dst[j]      = f2h(e * c - o * s);
        dst[j + 32] = f2h(e * s + o * c);
    }
}

// ---------------------------------------------------------------------------
// f16 MFMA GEMM for QKV (f16 out), 128x64 tile, GLDS + XOR swizzle +
// double-buffered LDS, one barrier/iter (round-12 structure).
// ---------------------------------------------------------------------------
__global__ __launch_bounds__(256)
void gemm_qkv(const ushort_t* __restrict__ A, const ushort_t* __restrict__ Bt,
              ushort_t* __restrict__ C, int M, int N, int K)
{
    __shared__ ushort_t As[2][128 * 32];
    __shared__ ushort_t Bs[2][64 * 32];

    const int tid  = threadIdx.x;
    const int wave = tid >> 6, lane = tid & 63;
    const int quad = lane >> 4, l16 = lane & 15;
    const int rowBase = blockIdx.y * 128, colBase = blockIdx.x * 64;
    const int wm = (wave >> 1) * 64, wn = (wave & 1) * 32;

    f32x4 acc[4][2];
    const f32x4 zz = {0.f, 0.f, 0.f, 0.f};
#pragma unroll
    for (int i = 0; i < 4; i++)
#pragma unroll
        for (int j = 0; j < 2; j++) acc[i][j] = zz;

    const int sr = wave * 32 + (lane >> 2);
    const int sc = ((lane & 3) ^ ((lane >> 3) & 3)) * 8;
    const ushort_t* Ag0 = A + (size_t)(rowBase + sr) * K + sc;
    const ushort_t* Ag1 = A + (size_t)(rowBase + sr + 16) * K + sc;
    const int segA0 = (wave * 2 + 0) * 512, segA1 = (wave * 2 + 1) * 512;
    const int br = wave * 16 + (lane >> 2);
    const ushort_t* Bg0 = Bt + (size_t)(colBase + br) * K + sc;
    const int segB = wave * 512;

    const int fcol = (quad ^ ((l16 >> 1) & 3)) * 8;

    GLDS(Ag0, &As[0][segA0]);
    GLDS(Ag1, &As[0][segA1]);
    GLDS(Bg0, &Bs[0][segB]);

    for (int k0 = 0; k0 < K; k0 += 32) {
        const int cur = (k0 >> 5) & 1, nxt = cur ^ 1;
        __syncthreads();
        if (k0 + 32 < K) {
            GLDS(Ag0 + k0 + 32, &As[nxt][segA0]);
            GLDS(Ag1 + k0 + 32, &As[nxt][segA1]);
            GLDS(Bg0 + k0 + 32, &Bs[nxt][segB]);
        }

        h16x8 af[4], bf[2];
#pragma unroll
        for (int mt = 0; mt < 4; mt++)
            af[mt] = *(const h16x8*)&As[cur][(wm + mt * 16 + l16) * 32 + fcol];
#pragma unroll
        for (int nt = 0; nt < 2; nt++)
            bf[nt] = *(const h16x8*)&Bs[cur][(wn + nt * 16 + l16) * 32 + fcol];
#pragma unroll
        for (int mt = 0; mt < 4; mt++)
#pragma unroll
            for (int nt = 0; nt < 2; nt++)
                acc[mt][nt] = MFMAH(af[mt], bf[nt], acc[mt][nt]);
    }

#pragma unroll
    for (int mt = 0; mt < 4; mt++)
#pragma unroll
        for (int nt = 0; nt < 2; nt++) {
            const int row = rowBase + wm + mt * 16 + quad * 4;
            const int col = colBase + wn + nt * 16 + l16;
#pragma unroll
            for (int r = 0; r < 4; r++)
                C[(size_t)(row + r) * N + col] = f2h(acc[mt][nt][r]);
        }
}

// ---------------------------------------------------------------------------
// MFMA flash attention. Round-20: r19 (in-register PV, raw v_exp) with:
//  (a) KVBLK 64->128: 8 tiles instead of 16, halves barrier count (32->16)
//      and doubles staging transaction size. Same 2-barrier pattern (r2/r3
//      proved pattern changes are poison; this only scales the tile).
//  (b) softmax denominator via MFMA16(ones, pbv): deletes ~96 VALU adds/
//      tile from the 42%-busy VALU pipe + the final shfl_xor pair.
// LDS 35.8KB (2 blocks/CU unchanged).
// ---------------------------------------------------------------------------
__global__ __launch_bounds__(256)
void attn_mfma(const ushort_t* __restrict__ Qb, const ushort_t* __restrict__ Kb,
               const ushort_t* __restrict__ Vt, ushort_t* __restrict__ Pnum,
               float* __restrict__ Pl)
{
    const int qt = blockIdx.x, h = blockIdx.y;
    const int b = blockIdx.z >> 1, chunk = blockIdx.z & 1;
    const int kvh = h >> 2;
    const int tid = threadIdx.x;
    const int wave = tid >> 6, lane = tid & 63;
    const int quad = lane >> 4, l16 = lane & 15;

    __shared__ ushort_t Ks[128][72];
    __shared__ ushort_t Vs[64][136];

    const int row0 = qt * 256 + wave * 64;
    h16x8 qf[4][2];
#pragma unroll
    for (int mt = 0; mt < 4; mt++) {
        const ushort_t* qp =
            Qb + ((size_t)(b * 16 + h) * NN + row0 + mt * 16 + l16) * 64 + quad * 8;
        qf[mt][0] = *(const h16x8*)qp;
        qf[mt][1] = *(const h16x8*)(qp + 32);
    }

    h16x4 ones;
#pragma unroll
    for (int i = 0; i < 4; i++) ones[i] = (_Float16)1.0f;

    const ushort_t* kbase = Kb + (size_t)(b * 4 + kvh) * NN * 64;
    const ushort_t* vbase = Vt + (size_t)(b * 256 + kvh * 64) * NN;
    const int key_lo = chunk * (NN / NSPLIT);          // 1024-key chunk
    const int rot = (qt + ((h & 3) << 2)) & (NTILE - 1);

    const int srow = tid >> 2, sseg = (tid & 3) * 8;
    const ushort_t* kp_lane = kbase + (size_t)srow * 64 + sseg;   // + key*64
    const ushort_t* vp_lane = vbase + (size_t)srow * NN + sseg;   // + key

    const f32x4 zz = {0.f, 0.f, 0.f, 0.f};
    f32x4 o[4][4];
#pragma unroll
    for (int mt = 0; mt < 4; mt++)
#pragma unroll
        for (int dt = 0; dt < 4; dt++) o[mt][dt] = zz;
    f32x4 lsum[4];
#pragma unroll
    for (int mt = 0; mt < 4; mt++) lsum[mt] = zz;

    const int key0 = key_lo + rot * KVBLK;
    uint4 kreg0 = *(const uint4*)(kp_lane + (size_t)key0 * 64);
    uint4 kreg1 = *(const uint4*)(kp_lane + (size_t)key0 * 64 + 32);
    uint4 kreg2 = *(const uint4*)(kp_lane + (size_t)(key0 + 64) * 64);
    uint4 kreg3 = *(const uint4*)(kp_lane + (size_t)(key0 + 64) * 64 + 32);
    uint4 vreg0 = *(const uint4*)(vp_lane + key0);
    uint4 vreg1 = *(const uint4*)(vp_lane + key0 + 32);
    uint4 vreg2 = *(const uint4*)(vp_lane + key0 + 64);
    uint4 vreg3 = *(const uint4*)(vp_lane + key0 + 96);

    for (int t = 0; t < NTILE; t++) {
        __syncthreads();
        *(uint4*)&Ks[srow][sseg]           = kreg0;
        *(uint4*)&Ks[srow][sseg + 32]      = kreg1;
        *(uint4*)&Ks[srow + 64][sseg]      = kreg2;
        *(uint4*)&Ks[srow + 64][sseg + 32] = kreg3;
        *(uint4*)&Vs[srow][sseg]           = vreg0;
        *(uint4*)&Vs[srow][sseg + 32]      = vreg1;
        *(uint4*)&Vs[srow][sseg + 64]      = vreg2;
        *(uint4*)&Vs[srow][sseg + 96]      = vreg3;
        __syncthreads();

        if (t < NTILE - 1) {
            const int kn = key_lo + ((rot + t + 1) & (NTILE - 1)) * KVBLK;
            kreg0 = *(const uint4*)(kp_lane + (size_t)kn * 64);
            kreg1 = *(const uint4*)(kp_lane + (size_t)kn * 64 + 32);
            kreg2 = *(const uint4*)(kp_lane + (size_t)(kn + 64) * 64);
            kreg3 = *(const uint4*)(kp_lane + (size_t)(kn + 64) * 64 + 32);
            vreg0 = *(const uint4*)(vp_lane + kn);
            vreg1 = *(const uint4*)(vp_lane + kn + 32);
            vreg2 = *(const uint4*)(vp_lane + kn + 64);
            vreg3 = *(const uint4*)(vp_lane + kn + 96);
        }

        // ---- fused per-kt: S^T = K Q^T -> exp2 -> pack -> PV (K=16, P in regs)
#pragma unroll
        for (int kt = 0; kt < 8; kt++) {
            h16x8 kf0 = *(const h16x8*)&Ks[kt * 16 + l16][quad * 8];
            h16x8 kf1 = *(const h16x8*)&Ks[kt * 16 + l16][32 + quad * 8];
            // V fragments for this kt: A-layout (K=16) = Vt[d][kt*16+quad*4+i]
            h16x4 va[4];
#pragma unroll
            for (int dt = 0; dt < 4; dt++)
                va[dt] = *(const h16x4*)&Vs[dt * 16 + l16][kt * 16 + quad * 4];

            uint2 pb[4];
#pragma unroll
            for (int mt = 0; mt < 4; mt++) {
                f32x4 st = MFMAH(kf0, qf[mt][0], zz);
                st = MFMAH(kf1, qf[mt][1], st);
                pb[mt].x = pk2h(EXP2(st[0]), EXP2(st[1]));
                pb[mt].y = pk2h(EXP2(st[2]), EXP2(st[3]));
            }
#pragma unroll
            for (int mt = 0; mt < 4; mt++) {
                const h16x4 pbv = *(const h16x4*)&pb[mt];
#pragma unroll
                for (int dt = 0; dt < 4; dt++)
                    o[mt][dt] = MFMA16(va[dt], pbv, o[mt][dt]);
                lsum[mt] = MFMA16(ones, pbv, lsum[mt]);
            }
        }
    }

    const size_t task0 = (size_t)(b * 16 + h) * NN + row0;
    ushort_t* np = Pnum + ((size_t)chunk * NTASK + task0) * 64;
#pragma unroll
    for (int mt = 0; mt < 4; mt++) {
        const float lt = lsum[mt][0];    // denom for q=l16 (rows identical)
        const float inv = 1.0f / lt;
#pragma unroll
        for (int dt = 0; dt < 4; dt++) {
            f32x4 v = o[mt][dt];
            uint2 pk;
            pk.x = pk2h(v[0] * inv, v[1] * inv);
            pk.y = pk2h(v[2] * inv, v[3] * inv);
            *(uint2*)&np[(size_t)(mt * 16 + l16) * 64 + dt * 16 + quad * 4] = pk;
        }
        if (quad == 0)
            Pl[(size_t)chunk * NTASK + task0 + mt * 16 + l16] = lt;
    }
}

// ---------------------------------------------------------------------------
// Wo GEMM with FUSED split-K combine: A[r][c] = (l0*ohat0 + l1*ohat1)/(l0+l1)
// computed during A-tile staging (manual ds_write into padded stride-40 LDS,
// 2 barriers/iter); B staged via GLDS + XOR swizzle, double-buffered.
// 128x64 tile, fp32 out. Deletes the combine kernel + Obuf round-trip.
// ---------------------------------------------------------------------------
__global__ __launch_bounds__(256)
void gemm_wo(const ushort_t* __restrict__ Pnum, const float* __restrict__ Pl,
             const ushort_t* __restrict__ WoT, float* __restrict__ C)
{
    __shared__ ushort_t As[2][128 * 40];   // padded rows: conflict-free b128
    __shared__ ushort_t Bs[2][64 * 32];

    const int tid  = threadIdx.x;
    const int wave = tid >> 6, lane = tid & 63;
    const int quad = lane >> 4, l16 = lane & 15;
    const int rowBase = blockIdx.y * 128, colBase = blockIdx.x * 64;
    const int wm = (wave >> 1) * 64, wn = (wave & 1) * 32;

    f32x4 acc[4][2];
    const f32x4 zz = {0.f, 0.f, 0.f, 0.f};
#pragma unroll
    for (int i = 0; i < 4; i++)
#pragma unroll
        for (int j = 0; j < 2; j++) acc[i][j] = zz;

    // A combine-staging: lane handles rows r0, r0+64; 8 cols at c8
    const int r0 = tid >> 2;             // 0..63
    const int c8 = (tid & 3) * 8;
    const int bB = rowBase >> 11;        // batch (scalar: 128 | 2048)
    const int n0 = (rowBase & (NN - 1)) + r0;

    // B staging (GLDS + swizzle)
    const int br = wave * 16 + (lane >> 2);
    const int sc = ((lane & 3) ^ ((lane >> 3) & 3)) * 8;
    const ushort_t* Bg0 = WoT + (size_t)(colBase + br) * D_MODEL + sc;
    const int segB = wave * 512;
    const int fcol = (quad ^ ((l16 >> 1) & 3)) * 8;

    uint4 a0c0, a0c1, a1c0, a1c1;
    float l00, l01, l10, l11;
    // prefetch A inputs for K-slice k0
#define PREFA(k0) { \
        const int h_ = (k0) >> 6; \
        const int d_ = ((k0) & 63) + c8; \
        const size_t t0_ = ((size_t)(bB * 16 + h_) << 11) + n0; \
        const size_t t1_ = t0_ + 64; \
        a0c0 = *(const uint4*)&Pnum[t0_ * 64 + d_]; \
        a0c1 = *(const uint4*)&Pnum[((size_t)NTASK + t0_) * 64 + d_]; \
        a1c0 = *(const uint4*)&Pnum[t1_ * 64 + d_]; \
        a1c1 = *(const uint4*)&Pnum[((size_t)NTASK + t1_) * 64 + d_]; \
        l00 = Pl[t0_]; l01 = Pl[NTASK + t0_]; \
        l10 = Pl[t1_]; l11 = Pl[NTASK + t1_]; \
    }

    PREFA(0);
    GLDS(Bg0, &Bs[0][segB]);

    for (int k0 = 0; k0 < D_MODEL; k0 += 32) {
        const int cur = (k0 >> 5) & 1, nxt = cur ^ 1;
        __syncthreads();     // prev-iter frag reads done; Bs[cur] GLDS drained

        // combine + stage A (two rows)
        {
            const float i0 = 1.f / (l00 + l01), w00 = l00 * i0, w01 = l01 * i0;
            const float i1 = 1.f / (l10 + l11), w10 = l10 * i1, w11 = l11 * i1;
            uint4 o0, o1;
            const uint_t* p0 = (const uint_t*)&a0c0;
            const uint_t* p1 = (const uint_t*)&a0c1;
            const uint_t* q0 = (const uint_t*)&a1c0;
            const uint_t* q1 = (const uint_t*)&a1c1;
            uint_t* po = (uint_t*)&o0;
            uint_t* qo = (uint_t*)&o1;
#pragma unroll
            for (int j = 0; j < 4; j++) {
                fp16x2 u = *(const fp16x2*)&p0[j];
                fp16x2 v = *(const fp16x2*)&p1[j];
                po[j] = pk2h(w00 * (float)u.x + w01 * (float)v.x,
                             w00 * (float)u.y + w01 * (float)v.y);
                fp16x2 s = *(const fp16x2*)&q0[j];
                fp16x2 r = *(const fp16x2*)&q1[j];
                qo[j] = pk2h(w10 * (float)s.x + w11 * (float)r.x,
                             w10 * (float)s.y + w11 * (float)r.y);
            }
            *(uint4*)&As[cur][r0 * 40 + c8]        = o0;
            *(uint4*)&As[cur][(r0 + 64) * 40 + c8] = o1;
        }
        __syncthreads();     // As[cur] visible to all waves

        if (k0 + 32 < D_MODEL) {
            GLDS(Bg0 + k0 + 32, &Bs[nxt][segB]);
            PREFA(k0 + 32);
        }

        h16x8 af[4], bf[2];
#pragma unroll
        for (int mt = 0; mt < 4; mt++)
            af[mt] = *(const h16x8*)&As[cur][(wm + mt * 16 + l16) * 40 + quad * 8];
#pragma unroll
        for (int nt = 0; nt < 2; nt++)
            bf[nt] = *(const h16x8*)&Bs[cur][(wn + nt * 16 + l16) * 32 + fcol];
#pragma unroll
        for (int mt = 0; mt < 4; mt++)
#pragma unroll
            for (int nt = 0; nt < 2; nt++)
                acc[mt][nt] = MFMAH(af[mt], bf[nt], acc[mt][nt]);
    }
#undef PREFA

#pragma unroll
    for (int mt = 0; mt < 4; mt++)
#pragma unroll
        for (int nt = 0; nt < 2; nt++) {
            const int row = rowBase + wm + mt * 16 + quad * 4;
            const int col = colBase + wn + nt * 16 + l16;
#pragma unroll
            for (int r = 0; r < 4; r++)
                C[(size_t)(row + r) * D_MODEL + col] = acc[mt][nt][r];
        }
}

// ---------------------------------------------------------------------------
extern "C" void kernel_launch(void* const* d_in, const int* in_sizes, int n_in,
                              void* d_out, int out_size, void* d_ws, size_t ws_size,
                              hipStream_t stream)
{
    const float* x    = (const float*)d_in[0];
    const float* cosp = (const float*)d_in[1];
    const float* sinp = (const float*)d_in[2];
    const float* Wq   = (const float*)d_in[3];
    const float* Wk   = (const float*)d_in[4];
    const float* Wv   = (const float*)d_in[5];
    const float* Wo   = (const float*)d_in[6];

    char* w = (char*)d_ws;
    ushort_t* xb     = (ushort_t*)w;                       w += (size_t)MROWS * D_MODEL * 2;
    ushort_t* WqkvT  = (ushort_t*)w;                       w += (size_t)QKVN * D_MODEL * 2;
    ushort_t* WoT    = (ushort_t*)w;                       w += (size_t)D_MODEL * D_MODEL * 2;
    ushort_t* QKVh   = (ushort_t*)w;                       w += (size_t)MROWS * QKVN * 2;
    ushort_t* Qbuf   = (ushort_t*)w;                       w += (size_t)MROWS * D_MODEL * 2;
    ushort_t* Kbuf   = (ushort_t*)w;                       w += (size_t)MROWS * KVDIM * 2;
    ushort_t* Vt     = (ushort_t*)w;                       w += (size_t)MROWS * KVDIM * 2;
    ushort_t* Pnum   = (ushort_t*)w;                       w += (size_t)NSPLIT * NTASK * 64 * 2;
    float*    Pl     = (float*)w;

    // --- fused prep (cast + 4 transposes): 1 dispatch
    prep_kernel<<<6656, 256, 0, stream>>>(x, Wq, Wk, Wv, Wo, xb, WqkvT, WoT);

    // --- fused QKV projection (f16 out)
    gemm_qkv<<<dim3(QKVN / 64, MROWS / 128), 256, 0, stream>>>(
        xb, WqkvT, QKVh, MROWS, QKVN, D_MODEL);

    // --- fused rope + V transpose: 1 dispatch
    ropevt_kernel<<<ROPEBLKS + 1024, 256, 0, stream>>>(
        QKVh, cosp, sinp, Qbuf, Kbuf, Vt);

    // --- attention (split-K x2, P in registers, KVBLK=128, MFMA denom)
    attn_mfma<<<dim3(NN / 256, NHEADS, BB * NSPLIT), 256, 0, stream>>>(
        Qbuf, Kbuf, Vt, Pnum, Pl);

    // --- output projection with fused combine (fp32 out)
    gemm_wo<<<dim3(D_MODEL / 64, MROWS / 128), 256, 0, stream>>>(
        Pnum, Pl, WoT, (float*)d_out);
}